// Round 11
// baseline (1166.070 us; speedup 1.0000x reference)
//
#include <hip/hip_runtime.h>
#include <hip/hip_bf16.h>
#include <math.h>

// Problem constants
constexpr int B = 128;
constexpr int T = 256;
constexpr int H = 200;       // hidden
constexpr int G4 = 800;      // 4*H
constexpr int BT = B * T;    // 32768
constexpr int K0 = 360, K0P = 384;   // layer0 input dim, padded to %32
constexpr int K1 = 400, K1P = 416;   // layer1 input dim, padded to %32

typedef __bf16 bf16x8 __attribute__((ext_vector_type(8)));
typedef float f32x4 __attribute__((ext_vector_type(4)));
typedef _Float16 half2v __attribute__((ext_vector_type(2)));
typedef unsigned uix4 __attribute__((ext_vector_type(4)));

__device__ __forceinline__ float bfr2f(unsigned short u) {
  union { unsigned int i; float f; } x;
  x.i = ((unsigned int)u) << 16;
  return x.f;
}
__device__ __forceinline__ unsigned short f2hu(float f) {
  _Float16 h = (_Float16)f;
  return *(unsigned short*)&h;
}
__device__ __forceinline__ half2v ash2(unsigned u) {
  union { unsigned v; half2v h; } x;
  x.v = u;
  return x.h;
}
__device__ __forceinline__ float sigm(float x) {
  return 1.0f / (1.0f + __expf(-x));
}
__device__ __forceinline__ float tanh_f(float x) {
  float e = __expf(2.0f * x);
  return (e - 1.0f) / (e + 1.0f);
}
// flag-dispatched raw load of a "float" input (f32 or bf16 storage)
__device__ __forceinline__ float ldraw(const void* p, size_t i, int f) {
  return f ? ((const float*)p)[i] : bfr2f(((const unsigned short*)p)[i]);
}

// ---------------------------------------------------------------------------
// Dtype detector (f32 vs bf16 storage of float inputs); see round-2 notes.
__global__ void detect_dtype(const unsigned short* __restrict__ raw,
                             int* __restrict__ flag) {
  __shared__ int cnt[256];
  int c = 0;
  for (int j = 0; j < 32; ++j) {
    unsigned short u = raw[1024 + threadIdx.x * 32 + j];
    int e = (u >> 7) & 0xFF;
    if (e >= 0xC0) ++c;
  }
  cnt[threadIdx.x] = c;
  __syncthreads();
  for (int off = 128; off > 0; off >>= 1) {
    if (threadIdx.x < off) cnt[threadIdx.x] += cnt[threadIdx.x + off];
    __syncthreads();
  }
  if (threadIdx.x == 0) *flag = (cnt[0] > 16) ? 1 : 0;
}

// Zero-fill (uix4 granularity)
__global__ void fill_zero(uix4* __restrict__ p, size_t n4) {
  size_t i = (size_t)blockIdx.x * blockDim.x + threadIdx.x;
  size_t stride = (size_t)gridDim.x * blockDim.x;
  uix4 z = {0u, 0u, 0u, 0u};
  for (; i < n4; i += stride) p[i] = z;
}

// ---------------------------------------------------------------------------
// Embedding concat into X0 [BT][K0P] — reads raw tables (flag-dispatched)
__global__ void embed_kernel(const int* __restrict__ words,
                             const int* __restrict__ pos,
                             const int* __restrict__ ner,
                             const void* __restrict__ emb_w,
                             const void* __restrict__ pos_w,
                             const void* __restrict__ ner_w,
                             __hip_bfloat16* __restrict__ X0,
                             const int* __restrict__ flag) {
  int bt = blockIdx.x;
  int f = *flag;
  int w = words[bt], p = pos[bt], nr = ner[bt];
  for (int j = threadIdx.x; j < K0P; j += blockDim.x) {
    float v;
    if (j < 300)       v = ldraw(emb_w, (size_t)w * 300 + j, f);
    else if (j < 330)  v = ldraw(pos_w, (size_t)p * 30 + (j - 300), f);
    else if (j < 360)  v = ldraw(ner_w, (size_t)nr * 30 + (j - 330), f);
    else               v = 0.0f;
    X0[(size_t)bt * K0P + j] = __float2bfloat16(v);
  }
}

// Pad-copy both directions' W_ih into one stacked [1600][Kp] bf16 matrix
__global__ void pad_copy2(const void* __restrict__ srcf,
                          const void* __restrict__ srcb,
                          __hip_bfloat16* __restrict__ dst, int K, int Kp,
                          const int* __restrict__ flag) {
  int r = blockIdx.x;  // 0..1599
  int f = *flag;
  const void* src = (r < G4) ? srcf : srcb;
  int rr = (r < G4) ? r : r - G4;
  for (int j = threadIdx.x; j < Kp; j += blockDim.x) {
    float v = (j < K) ? ldraw(src, (size_t)rr * K + j, f) : 0.0f;
    dst[(size_t)r * Kp + j] = __float2bfloat16(v);
  }
}

// Pack all 4 W_hh [800][200] into k-pairwise FP16 dwords (fp16 exact for
// bf16-derived weights; enables v_dot2_f32_f16: 1 instr / 2 MACs, f32 acc).
__global__ void pack_whh4(const void* __restrict__ s0, const void* __restrict__ s1,
                          const void* __restrict__ s2, const void* __restrict__ s3,
                          unsigned* __restrict__ dst,
                          const int* __restrict__ flag) {
  int idx = blockIdx.x * blockDim.x + threadIdx.x;  // 4*800*100
  if (idx >= 4 * G4 * 100) return;
  int f = *flag;
  int m = idx / (G4 * 100);
  int loc = idx - m * (G4 * 100);
  const void* src = (m == 0) ? s0 : (m == 1) ? s1 : (m == 2) ? s2 : s3;
  int n = loc / 100, p = loc - n * 100;
  float lo_f = ldraw(src, (size_t)n * 200 + 2 * p, f);
  float hi_f = ldraw(src, (size_t)n * 200 + 2 * p + 1, f);
  dst[idx] = (unsigned)f2hu(lo_f) | ((unsigned)f2hu(hi_f) << 16);
}

// ---------------------------------------------------------------------------
// MFMA GEMM v3 (verified round 9): LDS-staged 128x128 tile, BK=64, double-
// buffered, XOR-swizzled, reg-staged global->LDS (T14 issue-early/write-late).
// NOTE: a global_load_lds variant (v4) hit two container-level bench failures
// in round 10; since it introduced new intrinsic surface it stays quarantined
// until it can be compile-validated out-of-band. v3 is the proven form.
__global__ __launch_bounds__(256) void gemm_bt(
    const __hip_bfloat16* __restrict__ A,
    const __hip_bfloat16* __restrict__ Bm,
    __hip_bfloat16* __restrict__ C,
    int N, int Kp) {
  const int tid = threadIdx.x;
  const int lane = tid & 63;
  const int wave = tid >> 6;           // 0..3
  const int l15 = lane & 15, quad = lane >> 4;
  const int wr = wave & 1, wc = wave >> 1;   // 2x2 wave grid, 64x64 each
  const int m0 = blockIdx.x * 128;
  const int n0 = blockIdx.y * 128;

  // [2 bufs][128 rows][8 chunks of 8 bf16] per matrix = 32 KB each
  __shared__ __align__(16) __hip_bfloat16 Ab[2][128 * 64];
  __shared__ __align__(16) __hip_bfloat16 Bb[2][128 * 64];

  f32x4 acc[4][4] = {};

  const int nk = (Kp + 63) >> 6;   // 384->6, 416->7

  // Per-thread staging chunks: j=0..3 -> A chunk c=tid+j*256 (c in [0,1024)),
  // j=4..7 -> B chunk c-1024. chunk c: row=c>>3, pos p=c&7, data qd=p^(row&7).
  uix4 st[8];
  auto stage_issue = [&](int kt) {
    const int k0 = kt << 6;
    #pragma unroll
    for (int j = 0; j < 8; ++j) {
      int c = tid + (j & 3) * 256;
      int row = c >> 3, p = c & 7;
      int qd = p ^ (row & 7);
      int kcol = k0 + qd * 8;
      uix4 z = {0u, 0u, 0u, 0u};
      if (kcol + 8 <= Kp) {
        if (j < 4) {
          st[j] = *(const uix4*)(A + (size_t)(m0 + row) * Kp + kcol);
        } else {
          int br = n0 + row; if (br > N - 1) br = N - 1;
          st[j] = *(const uix4*)(Bm + (size_t)br * Kp + kcol);
        }
      } else {
        st[j] = z;
      }
    }
  };
  auto stage_write = [&](int buf) {
    #pragma unroll
    for (int j = 0; j < 8; ++j) {
      int c = tid + (j & 3) * 256;
      if (j < 4) *(uix4*)((char*)&Ab[buf][0] + c * 16) = st[j];
      else       *(uix4*)((char*)&Bb[buf][0] + c * 16) = st[j];
    }
  };

  // prologue: tile 0 into buf 0
  stage_issue(0);
  stage_write(0);
  __syncthreads();

  for (int kt = 0; kt < nk; ++kt) {
    const int buf = kt & 1;
    if (kt + 1 < nk) stage_issue(kt + 1);   // loads in flight over compute

    #pragma unroll
    for (int k32 = 0; k32 < 2; ++k32) {
      bf16x8 a[4], b[4];
      #pragma unroll
      for (int mi = 0; mi < 4; ++mi) {
        int row = wr * 64 + mi * 16 + l15;
        int p = (k32 * 4 + quad) ^ (row & 7);
        a[mi] = *(const bf16x8*)((const char*)&Ab[buf][0] + (row * 8 + p) * 16);
      }
      #pragma unroll
      for (int ni = 0; ni < 4; ++ni) {
        int row = wc * 64 + ni * 16 + l15;
        int p = (k32 * 4 + quad) ^ (row & 7);
        b[ni] = *(const bf16x8*)((const char*)&Bb[buf][0] + (row * 8 + p) * 16);
      }
      #pragma unroll
      for (int mi = 0; mi < 4; ++mi)
        #pragma unroll
        for (int ni = 0; ni < 4; ++ni)
          acc[mi][ni] = __builtin_amdgcn_mfma_f32_16x16x32_bf16(
              a[mi], b[ni], acc[mi][ni], 0, 0, 0);
    }

    if (kt + 1 < nk) stage_write((kt + 1) & 1);  // vmcnt waits inserted here
    __syncthreads();
  }

  #pragma unroll
  for (int mi = 0; mi < 4; ++mi)
    #pragma unroll
    for (int ni = 0; ni < 4; ++ni)
      #pragma unroll
      for (int r = 0; r < 4; ++r) {
        int row = m0 + wr * 64 + mi * 16 + quad * 4 + r;
        int col = n0 + wc * 64 + ni * 16 + l15;
        if (col < N)
          C[(size_t)row * N + col] = __float2bfloat16(acc[mi][ni][r]);
      }
}

// ---------------------------------------------------------------------------
// LSTM recurrence v7 (verbatim, best verified: 360 µs/dispatch; rounds 2-8
// established this structure's floor — prefetch/counted-vmcnt/asm-dot/
// 1-barrier/16-wave variants all measured 368-414).
__global__ __launch_bounds__(512, 2) void lstm_row(
    const __hip_bfloat16* __restrict__ Gpre,   // [B*T][1600]  x@W_ih^T (no bias)
    const unsigned* __restrict__ Wpack,        // [2][800][100] packed fp16 k-pairs
    const void* __restrict__ bias_f_raw,       // [800] raw
    const void* __restrict__ bias_b_raw,       // [800] raw
    const int* __restrict__ masks,             // [B][T], 1 = pad
    __hip_bfloat16* __restrict__ out,          // [B][T][ostride] (pre-zeroed)
    int ostride,
    float* __restrict__ final_h,               // [B][400] = [hb | hf], or nullptr
    const int* __restrict__ flag)
{
  const int tid = threadIdx.x;
  const int dir = blockIdx.x >> 7;
  const int row = blockIdx.x & 127;
  const int wave = tid >> 6;
  const int lane = tid & 63;
  const int kq = wave & 3;                    // k-quarter, wave-uniform
  const int gs = ((wave >> 2) << 6) | lane;   // 0..127
  const bool tail = (gs >= 96);               // handles gates 768..799

  __shared__ __align__(16) _Float16 hsh[256];  // 4 quarters x 64 halfs
  __shared__ float parts[4 * 804];             // [kq][gate(+4)], 12864 B
  __shared__ int lensh[256];                   // length reduce scratch
  __shared__ int bigbuf[21504];                // 86016 B: [0:3232)=tail W
                                               // (stride 101); rest pads LDS
                                               // >80KB so 1 block/CU

  const unsigned* wb = Wpack + (size_t)dir * G4 * 100;

  // --- stage tail-gate weights (768..799), stride 101 ---
  for (int i = tid; i < 3200; i += 512) {
    int g = i / 100, c = i - g * 100;
    bigbuf[g * 101 + c] = (int)wb[(768 + g) * 100 + c];
  }
  // --- per-row length: count of keep tokens (pads are a contiguous tail) ---
  if (tid < 256) lensh[tid] = (masks[row * T + tid] == 0) ? 1 : 0;

  // --- register weights: 150 dwords/thread, compile-time indices ---
  unsigned w[6][25];
  {
    const unsigned* s = wb + gs * 100 + kq * 25;
    #pragma unroll
    for (int j = 0; j < 6; ++j)
      #pragma unroll
      for (int p = 0; p < 25; ++p)
        w[j][p] = s[12800 * j + p];
  }
  const unsigned* wt = (const unsigned*)&bigbuf[(gs - 96) * 101 + kq * 25];

  // --- reduce-thread constants (u = hidden unit) ---
  const int u = tid;
  const int f = *flag;
  const void* braw = dir ? bias_b_raw : bias_f_raw;
  float bI = 0.f, bF = 0.f, bG = 0.f, bO = 0.f;
  if (u < 200) {
    bI = ldraw(braw, u, f);
    bF = ldraw(braw, 200 + u, f);
    bG = ldraw(braw, 400 + u, f);
    bO = ldraw(braw, 600 + u, f);
  }

  if (tid < 256) hsh[tid] = (_Float16)0.0f;   // zero all quarters incl. pads
  float creg = 0.0f, hreg = 0.0f;
  __syncthreads();

  // --- length tree-reduce ---
  for (int off = 128; off > 0; off >>= 1) {
    if (tid < off) lensh[tid] += lensh[tid + off];
    __syncthreads();
  }
  const int len = lensh[0];   // in [128, 256]

  const unsigned short* gp = (const unsigned short*)Gpre + dir * 800;
  const size_t gbase = (size_t)row * T;
  const uix4* hvp = (const uix4*)((const char*)hsh + kq * 128);
  const int hwrite = (u / 50) * 64 + (u % 50);  // quarter-padded h index

  #pragma unroll 1
  for (int tt = 0; tt < len; ++tt) {
    const int t = dir ? (len - 1 - tt) : tt;
    const size_t goff = (gbase + t) * 1600;
    // prefetch gate pre-activations (consumed in the reduce phase)
    unsigned short qI = 0, qF = 0, qG = 0, qO = 0;
    if (u < 200) {
      qI = gp[goff + u];
      qF = gp[goff + 200 + u];
      qG = gp[goff + 400 + u];
      qO = gp[goff + 600 + u];
    }

    // --- h plane: 7 broadcast b128 reads of this k-quarter ---
    uix4 hb[7];
    #pragma unroll
    for (int i = 0; i < 7; ++i) hb[i] = hvp[i];

    // --- dot phase: fp16 dot2, f32 accumulate ---
    float a0 = 0.f, a1 = 0.f, a2 = 0.f, a3 = 0.f, a4 = 0.f, a5 = 0.f;
    #pragma unroll
    for (int p = 0; p < 25; ++p) {
      half2v h2 = ash2(hb[p >> 2][p & 3]);
      a0 = __builtin_amdgcn_fdot2(ash2(w[0][p]), h2, a0, false);
      a1 = __builtin_amdgcn_fdot2(ash2(w[1][p]), h2, a1, false);
      a2 = __builtin_amdgcn_fdot2(ash2(w[2][p]), h2, a2, false);
      a3 = __builtin_amdgcn_fdot2(ash2(w[3][p]), h2, a3, false);
      a4 = __builtin_amdgcn_fdot2(ash2(w[4][p]), h2, a4, false);
      a5 = __builtin_amdgcn_fdot2(ash2(w[5][p]), h2, a5, false);
    }
    const int pb = kq * 804;
    parts[pb + gs]        = a0;
    parts[pb + 128 + gs]  = a1;
    parts[pb + 256 + gs]  = a2;
    parts[pb + 384 + gs]  = a3;
    parts[pb + 512 + gs]  = a4;
    parts[pb + 640 + gs]  = a5;
    if (tail) {
      float a6 = 0.f;
      #pragma unroll
      for (int p = 0; p < 25; ++p)
        a6 = __builtin_amdgcn_fdot2(ash2(wt[p]), ash2(hb[p >> 2][p & 3]), a6, false);
      parts[pb + 672 + gs] = a6;   // gate 768+(gs-96)
    }
    __syncthreads();

    // --- reduce + nonlinearity (threads 0..199); no pads inside [0,len) ---
    if (u < 200) {
      float gi = parts[u]       + parts[804 + u]       + parts[1608 + u]       + parts[2412 + u]       + bI + bfr2f(qI);
      float gf = parts[200 + u] + parts[804 + 200 + u] + parts[1608 + 200 + u] + parts[2412 + 200 + u] + bF + bfr2f(qF);
      float gg = parts[400 + u] + parts[804 + 400 + u] + parts[1608 + 400 + u] + parts[2412 + 400 + u] + bG + bfr2f(qG);
      float go = parts[600 + u] + parts[804 + 600 + u] + parts[1608 + 600 + u] + parts[2412 + 600 + u] + bO + bfr2f(qO);
      float si = sigm(gi), sf = sigm(gf), so = sigm(go);
      float cn = sf * creg + si * tanh_f(gg);
      float hn = so * tanh_f(cn);
      creg = cn;
      hreg = hn;
      hsh[hwrite] = (_Float16)hn;
      out[((size_t)row * T + t) * ostride + dir * H + u] = __float2bfloat16(hn);
    }
    __syncthreads();
  }

  if (final_h != nullptr && u < 200) {
    // glob_h = [hb1 | hf1]: backward dir -> cols 0..199, forward -> 200..399
    int col = dir ? u : (H + u);
    final_h[(size_t)row * 400 + col] = hreg;
  }
}

// ---------------------------------------------------------------------------
// Span sums v2: chunked (t-chunk x d-octet) with bf16x8 row loads.
// Threads: tc = tid>>6 (t-chunk of 64), dv = tid&63 (d-octet, active < 50).
// Flag loads are wave-uniform (scalar); rows loaded only on span hits.
__global__ __launch_bounds__(256) void span_sum(
    const __hip_bfloat16* __restrict__ rnn,   // [B][T][400]
    const int* __restrict__ masks,
    const int* __restrict__ subj_pos,
    const int* __restrict__ obj_pos,
    float* __restrict__ obj_h,   // [B][400]
    float* __restrict__ subj_h)  // [B][400]
{
  int b = blockIdx.x;
  int tc = threadIdx.x >> 6;
  int dv = threadIdx.x & 63;
  __shared__ float aS[4][400];
  __shared__ float aO[4][400];

  float ss[8] = {}, so[8] = {};
  if (dv < 50) {
    for (int t = tc * 64; t < tc * 64 + 64; ++t) {
      int m = masks[b * T + t];
      int fs = (subj_pos[b * T + t] + m) == 0;
      int fo = (obj_pos[b * T + t] + m) == 0;
      if (fs | fo) {
        uix4 v = *(const uix4*)(rnn + ((size_t)b * T + t) * 400 + dv * 8);
        #pragma unroll
        for (int j = 0; j < 4; ++j) {
          float lo = bfr2f((unsigned short)(v[j] & 0xFFFF));
          float hi = bfr2f((unsigned short)(v[j] >> 16));
          if (fs) { ss[2 * j] += lo; ss[2 * j + 1] += hi; }
          if (fo) { so[2 * j] += lo; so[2 * j + 1] += hi; }
        }
      }
    }
    #pragma unroll
    for (int k = 0; k < 8; ++k) {
      aS[tc][dv * 8 + k] = ss[k];
      aO[tc][dv * 8 + k] = so[k];
    }
  }
  __syncthreads();
  for (int d = threadIdx.x; d < 400; d += 256) {
    subj_h[(size_t)b * 400 + d] = aS[0][d] + aS[1][d] + aS[2][d] + aS[3][d];
    obj_h[(size_t)b * 400 + d]  = aO[0][d] + aO[1][d] + aO[2][d] + aO[3][d];
  }
}

// ---------------------------------------------------------------------------
// Fused single-query attention pooling v3: ONE block per batch row computes
// all 3 queries (obj/subj/glob). Rationale (round-10 budget): the v2 kernel's
// 3 qi-blocks per b each re-read the same ~400KB rnn[b] slab — 3x redundant
// traffic on the largest non-GEMM item. Fused: kv row loaded once, dotted
// against 3 queries (extra VALU is free, kernel is memory-bound); 3 sequential
// LDS softmaxes; single phase-2 sweep with 3 accumulators. Numerics per query
// identical to v2 (same reduction orders). Pad rows: ps==0 exactly.
__global__ __launch_bounds__(256) void attn_pool3(
    const float* __restrict__ qbuf,           // [3][B][400]
    const __hip_bfloat16* __restrict__ rnn,   // [B][T][400]
    const int* __restrict__ masks,
    float* __restrict__ outp)                 // [3][B][400]
{
  int b = blockIdx.x;
  int tid = threadIdx.x;
  __shared__ float qs[3][400];
  __shared__ float ps[3][256];
  __shared__ float red[256];
  __shared__ float acc12[4][1200];   // [t-chunk][qi*400+d]

  for (int d = tid; d < 1200; d += 256) {
    int qi = d / 400, dm = d - qi * 400;
    qs[qi][dm] = qbuf[((size_t)qi * B + b) * 400 + dm];
  }
  __syncthreads();

  // --- phase 1: scores for all 3 queries, kv row loaded once ---
  int t = tid;
  const uix4* kvv = (const uix4*)(rnn + ((size_t)b * T + t) * 400);
  float s0 = 0.f, s1 = 0.f, s2 = 0.f;
  #pragma unroll 5
  for (int i = 0; i < 50; ++i) {
    uix4 v = kvv[i];
    #pragma unroll
    for (int j = 0; j < 4; ++j) {
      float lo = bfr2f((unsigned short)(v[j] & 0xFFFF));
      float hi = bfr2f((unsigned short)(v[j] >> 16));
      int d0 = 8 * i + 2 * j;
      s0 += lo * qs[0][d0] + hi * qs[0][d0 + 1];
      s1 += lo * qs[1][d0] + hi * qs[1][d0 + 1];
      s2 += lo * qs[2][d0] + hi * qs[2][d0 + 1];
    }
  }
  float sq[3] = {s0 * 0.05f, s1 * 0.05f, s2 * 0.05f};  // 1/sqrt(400)
  if (masks[b * T + t] != 0) { sq[0] = -1e9f; sq[1] = -1e9f; sq[2] = -1e9f; }

  // --- 3 sequential softmaxes (barriers in uniform control flow) ---
  for (int qi = 0; qi < 3; ++qi) {
    red[t] = sq[qi];
    __syncthreads();
    for (int off = 128; off > 0; off >>= 1) {
      if (t < off) red[t] = fmaxf(red[t], red[t + off]);
      __syncthreads();
    }
    float mx = red[0];
    __syncthreads();
    float e = expf(sq[qi] - mx);
    red[t] = e;
    __syncthreads();
    for (int off = 128; off > 0; off >>= 1) {
      if (t < off) red[t] += red[t + off];
      __syncthreads();
    }
    ps[qi][t] = e / red[0];
    __syncthreads();
  }

  // --- phase 2: single rnn sweep, 3 accumulators ---
  int tc = tid >> 6, dv = tid & 63;
  float a0[8] = {}, a1[8] = {}, a2[8] = {};
  if (dv < 50) {
    for (int t2 = tc * 64; t2 < tc * 64 + 64; ++t2) {
      float w0 = ps[0][t2], w1 = ps[1][t2], w2 = ps[2][t2];  // wave-uniform
      if ((w0 != 0.f) || (w1 != 0.f) || (w2 != 0.f)) {
        uix4 v = *(const uix4*)(rnn + ((size_t)b * T + t2) * 400 + dv * 8);
        #pragma unroll
        for (int j = 0; j < 4; ++j) {
          float lo = bfr2f((unsigned short)(v[j] & 0xFFFF));
          float hi = bfr2f((unsigned short)(v[j] >> 16));
          a0[2 * j] += w0 * lo; a0[2 * j + 1] += w0 * hi;
          a1[2 * j] += w1 * lo; a1[2 * j + 1] += w1 * hi;
          a2[2 * j] += w2 * lo; a2[2 * j + 1] += w2 * hi;
        }
      }
    }
    #pragma unroll
    for (int k = 0; k < 8; ++k) {
      acc12[tc][dv * 8 + k]       = a0[k];
      acc12[tc][400 + dv * 8 + k] = a1[k];
      acc12[tc][800 + dv * 8 + k] = a2[k];
    }
  }
  __syncthreads();
  for (int d = tid; d < 1200; d += 256) {
    int qi = d / 400, dm = d - qi * 400;
    outp[((size_t)qi * B + b) * 400 + dm] =
        acc12[0][d] + acc12[1][d] + acc12[2][d] + acc12[3][d];
  }
}

// ---------------------------------------------------------------------------
// Head — reads all weights raw (flag-dispatched), writes bf16 or f32 per flag
__global__ __launch_bounds__(256) void final_head(
    const float* __restrict__ attn,   // [3][B][400]: 0=obj,1=subj,2=glob
    const void* __restrict__ wo_w, const void* __restrict__ wo_b,
    const void* __restrict__ ws_w, const void* __restrict__ ws_b,
    const void* __restrict__ wg_w, const void* __restrict__ wg_b,
    const void* __restrict__ cls_w, const void* __restrict__ cls_b,
    void* __restrict__ outp,          // [B][2]
    const int* __restrict__ flag)
{
  int b = blockIdx.x;
  int f = *flag;
  __shared__ float hs[H];
  int j = threadIdx.x;
  if (j < H) {
    float acc = ldraw(wo_b, j, f) + ldraw(ws_b, j, f) + ldraw(wg_b, j, f);
    const float* oa = attn + ((size_t)0 * B + b) * 400;
    const float* sa = attn + ((size_t)1 * B + b) * 400;
    const float* ga = attn + ((size_t)2 * B + b) * 400;
    for (int d = 0; d < 400; ++d) {
      acc += oa[d] * ldraw(wo_w, (size_t)j * 400 + d, f);
      acc += sa[d] * ldraw(ws_w, (size_t)j * 400 + d, f);
      acc += ga[d] * ldraw(wg_w, (size_t)j * 400 + d, f);
    }
    hs[j] = fmaxf(acc, 0.0f);
  }
  __syncthreads();
  if (j < 2) {
    float a = ldraw(cls_b, j, f);
    for (int k = 0; k < H; ++k)
      a += hs[k] * ldraw(cls_w, (size_t)j * H + k, f);
    if (f) ((float*)outp)[b * 2 + j] = a;
    else   ((__hip_bfloat16*)outp)[b * 2 + j] = __float2bfloat16(a);
  }
}

// ---------------------------------------------------------------------------
// Workspace layout (bytes)
constexpr size_t O_X0   = 0;            // 32768*384*2  = 25165824
constexpr size_t O_X1   = 25165824;     // 32768*416*2  = 27262976
constexpr size_t O_GPRE = 52428800;     // 32768*1600*2 = 104857600
constexpr size_t O_RNN  = 157286400;    // 32768*400*2  = 26214400
constexpr size_t O_WIH0 = 183500800;    // 1600*384*2   = 1228800
constexpr size_t O_WIH1 = 184729600;    // 1600*416*2   = 1331200
constexpr size_t O_WPK  = 186060800;    // 4*800*100*4  = 1280000
constexpr size_t O_Q    = 187340800;    // 3*128*400*4  = 614400
constexpr size_t O_ATT  = 187955200;    // 614400
constexpr size_t O_FLAG = 188569600;    // 256

extern "C" void kernel_launch(void* const* d_in, const int* in_sizes, int n_in,
                              void* d_out, int out_size, void* d_ws, size_t ws_size,
                              hipStream_t stream) {
  (void)in_sizes; (void)n_in; (void)out_size; (void)ws_size;

  const int* words = (const int*)d_in[0];
  const int* masks = (const int*)d_in[1];
  const int* pos   = (const int*)d_in[2];
  const int* ner   = (const int*)d_in[3];
  const int* subj  = (const int*)d_in[4];
  const int* obj   = (const int*)d_in[5];
  const void* emb_w = d_in[6];
  const void* pos_w = d_in[7];
  const void* ner_w = d_in[8];
  const void* wih[4]  = {d_in[9],  d_in[12], d_in[15], d_in[18]};
  const void* whh[4]  = {d_in[10], d_in[13], d_in[16], d_in[19]};
  const void* bias[4] = {d_in[11], d_in[14], d_in[17], d_in[20]};
  const void* wo_w = d_in[21]; const void* wo_b = d_in[22];
  const void* ws_w = d_in[23]; const void* ws_b = d_in[24];
  const void* wg_w = d_in[25]; const void* wg_b = d_in[26];
  const void* cls_w = d_in[27]; const void* cls_b = d_in[28];

  char* ws = (char*)d_ws;
  __hip_bfloat16* X0   = (__hip_bfloat16*)(ws + O_X0);
  __hip_bfloat16* X1   = (__hip_bfloat16*)(ws + O_X1);
  __hip_bfloat16* Gpre = (__hip_bfloat16*)(ws + O_GPRE);   // [BT][1600]
  __hip_bfloat16* RNN  = (__hip_bfloat16*)(ws + O_RNN);
  __hip_bfloat16* wih0p = (__hip_bfloat16*)(ws + O_WIH0);  // [1600][384]
  __hip_bfloat16* wih1p = (__hip_bfloat16*)(ws + O_WIH1);  // [1600][416]
  unsigned* Wpack = (unsigned*)(ws + O_WPK);               // [4][800][100]
  float* qbuf = (float*)(ws + O_Q);    // [3][B][400]: obj, subj, glob
  float* attb = (float*)(ws + O_ATT);  // [3][B][400]
  int* flag = (int*)(ws + O_FLAG);

  // --- dtype detect + weight prep (all read raw, flag-dispatched) ---
  detect_dtype<<<1, 256, 0, stream>>>((const unsigned short*)emb_w, flag);
  pack_whh4<<<1250, 256, 0, stream>>>(whh[0], whh[1], whh[2], whh[3], Wpack, flag);
  pad_copy2<<<1600, 128, 0, stream>>>(wih[0], wih[1], wih0p, K0, K0P, flag);
  pad_copy2<<<1600, 128, 0, stream>>>(wih[2], wih[3], wih1p, K1, K1P, flag);

  // --- embedding + output-buffer zero fills (lstm skips padded steps) ---
  embed_kernel<<<BT, 128, 0, stream>>>(words, pos, ner, emb_w, pos_w, ner_w, X0, flag);
  fill_zero<<<1024, 256, 0, stream>>>((uix4*)X1, (size_t)BT * K1P * 2 / 16);
  fill_zero<<<1024, 256, 0, stream>>>((uix4*)RNN, (size_t)BT * 400 * 2 / 16);

  dim3 ggrid(BT / 128, 13);  // 128x128 tiles, N = 1600 (both dirs fused)

  // --- layer 0 ---
  gemm_bt<<<ggrid, 256, 0, stream>>>(X0, wih0p, Gpre, 1600, K0P);
  lstm_row<<<256, 512, 0, stream>>>(Gpre, Wpack, bias[0], bias[1], masks,
                                    X1, K1P, nullptr, flag);

  // --- layer 1 ---
  gemm_bt<<<ggrid, 256, 0, stream>>>(X1, wih1p, Gpre, 1600, K1P);
  float* qglob = qbuf + (size_t)2 * B * 400;
  lstm_row<<<256, 512, 0, stream>>>(Gpre, Wpack + (size_t)2 * G4 * 100,
                                    bias[2], bias[3], masks,
                                    RNN, 400, qglob, flag);

  // --- span sums (obj -> slot0, subj -> slot1) ---
  span_sum<<<B, 256, 0, stream>>>(RNN, masks, subj, obj,
                                  qbuf, qbuf + (size_t)B * 400);

  // --- fused attention pooling (3 queries, one block per batch row) ---
  attn_pool3<<<B, 256, 0, stream>>>(qbuf, RNN, masks, attb);

  // --- head (raw weights) ---
  final_head<<<B, 256, 0, stream>>>(attb, wo_w, wo_b, ws_w, ws_b, wg_w, wg_b,
                                    cls_w, cls_b, d_out, flag);
}

// Round 12
// 1143.441 us; speedup vs baseline: 1.0198x; 1.0198x over previous
//
#include <hip/hip_runtime.h>
#include <hip/hip_bf16.h>
#include <math.h>

// Problem constants
constexpr int B = 128;
constexpr int T = 256;
constexpr int H = 200;       // hidden
constexpr int G4 = 800;      // 4*H
constexpr int BT = B * T;    // 32768
constexpr int K0 = 360, K0P = 384;   // layer0 input dim, padded to %32
constexpr int K1 = 400, K1P = 416;   // layer1 input dim, padded to %32

typedef __bf16 bf16x8 __attribute__((ext_vector_type(8)));
typedef float f32x4 __attribute__((ext_vector_type(4)));
typedef _Float16 half2v __attribute__((ext_vector_type(2)));
typedef unsigned uix4 __attribute__((ext_vector_type(4)));

__device__ __forceinline__ float bfr2f(unsigned short u) {
  union { unsigned int i; float f; } x;
  x.i = ((unsigned int)u) << 16;
  return x.f;
}
__device__ __forceinline__ unsigned short f2hu(float f) {
  _Float16 h = (_Float16)f;
  return *(unsigned short*)&h;
}
__device__ __forceinline__ half2v ash2(unsigned u) {
  union { unsigned v; half2v h; } x;
  x.v = u;
  return x.h;
}
__device__ __forceinline__ float sigm(float x) {
  return 1.0f / (1.0f + __expf(-x));
}
__device__ __forceinline__ float tanh_f(float x) {
  float e = __expf(2.0f * x);
  return (e - 1.0f) / (e + 1.0f);
}
// flag-dispatched raw load of a "float" input (f32 or bf16 storage)
__device__ __forceinline__ float ldraw(const void* p, size_t i, int f) {
  return f ? ((const float*)p)[i] : bfr2f(((const unsigned short*)p)[i]);
}

// ---------------------------------------------------------------------------
// Dtype detector (f32 vs bf16 storage of float inputs); see round-2 notes.
__global__ void detect_dtype(const unsigned short* __restrict__ raw,
                             int* __restrict__ flag) {
  __shared__ int cnt[256];
  int c = 0;
  for (int j = 0; j < 32; ++j) {
    unsigned short u = raw[1024 + threadIdx.x * 32 + j];
    int e = (u >> 7) & 0xFF;
    if (e >= 0xC0) ++c;
  }
  cnt[threadIdx.x] = c;
  __syncthreads();
  for (int off = 128; off > 0; off >>= 1) {
    if (threadIdx.x < off) cnt[threadIdx.x] += cnt[threadIdx.x + off];
    __syncthreads();
  }
  if (threadIdx.x == 0) *flag = (cnt[0] > 16) ? 1 : 0;
}

// Zero-fill two regions in one launch (uix4 granularity)
__global__ void fill_zero2(uix4* __restrict__ p0, size_t n0,
                           uix4* __restrict__ p1, size_t n1) {
  size_t i = (size_t)blockIdx.x * blockDim.x + threadIdx.x;
  size_t stride = (size_t)gridDim.x * blockDim.x;
  uix4 z = {0u, 0u, 0u, 0u};
  size_t nt = n0 + n1;
  for (; i < nt; i += stride) {
    if (i < n0) p0[i] = z;
    else        p1[i - n0] = z;
  }
}

// ---------------------------------------------------------------------------
// Embedding concat into X0 [BT][K0P] v2: 8 tokens per 256-thread block
// (32 lanes/token, 12 elems/lane). Round-12 rationale: the 1-token/128-thr
// version launched 32768 tiny blocks — dispatch overhead dominated a kernel
// whose data floor is ~15 µs. Same loads/stores, 8x fewer blocks.
__global__ __launch_bounds__(256) void embed_kernel(
    const int* __restrict__ words,
    const int* __restrict__ pos,
    const int* __restrict__ ner,
    const void* __restrict__ emb_w,
    const void* __restrict__ pos_w,
    const void* __restrict__ ner_w,
    __hip_bfloat16* __restrict__ X0,
    const int* __restrict__ flag) {
  int bt = blockIdx.x * 8 + (threadIdx.x >> 5);
  int j0 = threadIdx.x & 31;
  int f = *flag;
  int w = words[bt], p = pos[bt], nr = ner[bt];
  for (int j = j0; j < K0P; j += 32) {
    float v;
    if (j < 300)       v = ldraw(emb_w, (size_t)w * 300 + j, f);
    else if (j < 330)  v = ldraw(pos_w, (size_t)p * 30 + (j - 300), f);
    else if (j < 360)  v = ldraw(ner_w, (size_t)nr * 30 + (j - 330), f);
    else               v = 0.0f;
    X0[(size_t)bt * K0P + j] = __float2bfloat16(v);
  }
}

// ---------------------------------------------------------------------------
// Merged weight prep (one launch replaces pack_whh4 + 2x pad_copy2):
//  blocks [0,1250):    pack all 4 W_hh into fp16 k-pair dwords
//  blocks [1250,2850): pad-copy W_ih layer0 -> [1600][K0P] bf16
//  blocks [2850,4450): pad-copy W_ih layer1 -> [1600][K1P] bf16
__global__ __launch_bounds__(256) void prep_weights(
    const void* __restrict__ whh0, const void* __restrict__ whh1,
    const void* __restrict__ whh2, const void* __restrict__ whh3,
    unsigned* __restrict__ wpack,
    const void* __restrict__ wih0f, const void* __restrict__ wih0b,
    __hip_bfloat16* __restrict__ wih0p,
    const void* __restrict__ wih1f, const void* __restrict__ wih1b,
    __hip_bfloat16* __restrict__ wih1p,
    const int* __restrict__ flag) {
  int blk = blockIdx.x;
  int f = *flag;
  if (blk < 1250) {
    int idx = blk * 256 + threadIdx.x;  // 4*800*100 = 320000
    if (idx >= 4 * G4 * 100) return;
    int m = idx / (G4 * 100);
    int loc = idx - m * (G4 * 100);
    const void* src = (m == 0) ? whh0 : (m == 1) ? whh1 : (m == 2) ? whh2 : whh3;
    int n = loc / 100, p = loc - n * 100;
    float lo_f = ldraw(src, (size_t)n * 200 + 2 * p, f);
    float hi_f = ldraw(src, (size_t)n * 200 + 2 * p + 1, f);
    wpack[idx] = (unsigned)f2hu(lo_f) | ((unsigned)f2hu(hi_f) << 16);
  } else if (blk < 2850) {
    int r = blk - 1250;  // 0..1599
    const void* src = (r < G4) ? wih0f : wih0b;
    int rr = (r < G4) ? r : r - G4;
    for (int j = threadIdx.x; j < K0P; j += 256) {
      float v = (j < K0) ? ldraw(src, (size_t)rr * K0 + j, f) : 0.0f;
      wih0p[(size_t)r * K0P + j] = __float2bfloat16(v);
    }
  } else {
    int r = blk - 2850;  // 0..1599
    const void* src = (r < G4) ? wih1f : wih1b;
    int rr = (r < G4) ? r : r - G4;
    for (int j = threadIdx.x; j < K1P; j += 256) {
      float v = (j < K1) ? ldraw(src, (size_t)rr * K1 + j, f) : 0.0f;
      wih1p[(size_t)r * K1P + j] = __float2bfloat16(v);
    }
  }
}

// ---------------------------------------------------------------------------
// MFMA GEMM v3 (verified round 9): LDS-staged 128x128 tile, BK=64, double-
// buffered, XOR-swizzled, reg-staged global->LDS (T14 issue-early/write-late).
// NOTE: a global_load_lds variant (v4) hit two container-level bench failures
// in round 10; quarantined pending out-of-band compile validation.
__global__ __launch_bounds__(256) void gemm_bt(
    const __hip_bfloat16* __restrict__ A,
    const __hip_bfloat16* __restrict__ Bm,
    __hip_bfloat16* __restrict__ C,
    int N, int Kp) {
  const int tid = threadIdx.x;
  const int lane = tid & 63;
  const int wave = tid >> 6;           // 0..3
  const int l15 = lane & 15, quad = lane >> 4;
  const int wr = wave & 1, wc = wave >> 1;   // 2x2 wave grid, 64x64 each
  const int m0 = blockIdx.x * 128;
  const int n0 = blockIdx.y * 128;

  // [2 bufs][128 rows][8 chunks of 8 bf16] per matrix = 32 KB each
  __shared__ __align__(16) __hip_bfloat16 Ab[2][128 * 64];
  __shared__ __align__(16) __hip_bfloat16 Bb[2][128 * 64];

  f32x4 acc[4][4] = {};

  const int nk = (Kp + 63) >> 6;   // 384->6, 416->7

  // Per-thread staging chunks: j=0..3 -> A chunk c=tid+j*256 (c in [0,1024)),
  // j=4..7 -> B chunk c-1024. chunk c: row=c>>3, pos p=c&7, data qd=p^(row&7).
  uix4 st[8];
  auto stage_issue = [&](int kt) {
    const int k0 = kt << 6;
    #pragma unroll
    for (int j = 0; j < 8; ++j) {
      int c = tid + (j & 3) * 256;
      int row = c >> 3, p = c & 7;
      int qd = p ^ (row & 7);
      int kcol = k0 + qd * 8;
      uix4 z = {0u, 0u, 0u, 0u};
      if (kcol + 8 <= Kp) {
        if (j < 4) {
          st[j] = *(const uix4*)(A + (size_t)(m0 + row) * Kp + kcol);
        } else {
          int br = n0 + row; if (br > N - 1) br = N - 1;
          st[j] = *(const uix4*)(Bm + (size_t)br * Kp + kcol);
        }
      } else {
        st[j] = z;
      }
    }
  };
  auto stage_write = [&](int buf) {
    #pragma unroll
    for (int j = 0; j < 8; ++j) {
      int c = tid + (j & 3) * 256;
      if (j < 4) *(uix4*)((char*)&Ab[buf][0] + c * 16) = st[j];
      else       *(uix4*)((char*)&Bb[buf][0] + c * 16) = st[j];
    }
  };

  // prologue: tile 0 into buf 0
  stage_issue(0);
  stage_write(0);
  __syncthreads();

  for (int kt = 0; kt < nk; ++kt) {
    const int buf = kt & 1;
    if (kt + 1 < nk) stage_issue(kt + 1);   // loads in flight over compute

    #pragma unroll
    for (int k32 = 0; k32 < 2; ++k32) {
      bf16x8 a[4], b[4];
      #pragma unroll
      for (int mi = 0; mi < 4; ++mi) {
        int row = wr * 64 + mi * 16 + l15;
        int p = (k32 * 4 + quad) ^ (row & 7);
        a[mi] = *(const bf16x8*)((const char*)&Ab[buf][0] + (row * 8 + p) * 16);
      }
      #pragma unroll
      for (int ni = 0; ni < 4; ++ni) {
        int row = wc * 64 + ni * 16 + l15;
        int p = (k32 * 4 + quad) ^ (row & 7);
        b[ni] = *(const bf16x8*)((const char*)&Bb[buf][0] + (row * 8 + p) * 16);
      }
      #pragma unroll
      for (int mi = 0; mi < 4; ++mi)
        #pragma unroll
        for (int ni = 0; ni < 4; ++ni)
          acc[mi][ni] = __builtin_amdgcn_mfma_f32_16x16x32_bf16(
              a[mi], b[ni], acc[mi][ni], 0, 0, 0);
    }

    if (kt + 1 < nk) stage_write((kt + 1) & 1);  // vmcnt waits inserted here
    __syncthreads();
  }

  #pragma unroll
  for (int mi = 0; mi < 4; ++mi)
    #pragma unroll
    for (int ni = 0; ni < 4; ++ni)
      #pragma unroll
      for (int r = 0; r < 4; ++r) {
        int row = m0 + wr * 64 + mi * 16 + quad * 4 + r;
        int col = n0 + wc * 64 + ni * 16 + l15;
        if (col < N)
          C[(size_t)row * N + col] = __float2bfloat16(acc[mi][ni][r]);
      }
}

// ---------------------------------------------------------------------------
// LSTM recurrence v7 (verbatim, best verified: 360 µs/dispatch; rounds 2-8
// established this structure's floor — prefetch/counted-vmcnt/asm-dot/
// 1-barrier/16-wave variants all measured 368-414).
__global__ __launch_bounds__(512, 2) void lstm_row(
    const __hip_bfloat16* __restrict__ Gpre,   // [B*T][1600]  x@W_ih^T (no bias)
    const unsigned* __restrict__ Wpack,        // [2][800][100] packed fp16 k-pairs
    const void* __restrict__ bias_f_raw,       // [800] raw
    const void* __restrict__ bias_b_raw,       // [800] raw
    const int* __restrict__ masks,             // [B][T], 1 = pad
    __hip_bfloat16* __restrict__ out,          // [B][T][ostride] (pre-zeroed)
    int ostride,
    float* __restrict__ final_h,               // [B][400] = [hb | hf], or nullptr
    const int* __restrict__ flag)
{
  const int tid = threadIdx.x;
  const int dir = blockIdx.x >> 7;
  const int row = blockIdx.x & 127;
  const int wave = tid >> 6;
  const int lane = tid & 63;
  const int kq = wave & 3;                    // k-quarter, wave-uniform
  const int gs = ((wave >> 2) << 6) | lane;   // 0..127
  const bool tail = (gs >= 96);               // handles gates 768..799

  __shared__ __align__(16) _Float16 hsh[256];  // 4 quarters x 64 halfs
  __shared__ float parts[4 * 804];             // [kq][gate(+4)], 12864 B
  __shared__ int lensh[256];                   // length reduce scratch
  __shared__ int bigbuf[21504];                // 86016 B: [0:3232)=tail W
                                               // (stride 101); rest pads LDS
                                               // >80KB so 1 block/CU

  const unsigned* wb = Wpack + (size_t)dir * G4 * 100;

  // --- stage tail-gate weights (768..799), stride 101 ---
  for (int i = tid; i < 3200; i += 512) {
    int g = i / 100, c = i - g * 100;
    bigbuf[g * 101 + c] = (int)wb[(768 + g) * 100 + c];
  }
  // --- per-row length: count of keep tokens (pads are a contiguous tail) ---
  if (tid < 256) lensh[tid] = (masks[row * T + tid] == 0) ? 1 : 0;

  // --- register weights: 150 dwords/thread, compile-time indices ---
  unsigned w[6][25];
  {
    const unsigned* s = wb + gs * 100 + kq * 25;
    #pragma unroll
    for (int j = 0; j < 6; ++j)
      #pragma unroll
      for (int p = 0; p < 25; ++p)
        w[j][p] = s[12800 * j + p];
  }
  const unsigned* wt = (const unsigned*)&bigbuf[(gs - 96) * 101 + kq * 25];

  // --- reduce-thread constants (u = hidden unit) ---
  const int u = tid;
  const int f = *flag;
  const void* braw = dir ? bias_b_raw : bias_f_raw;
  float bI = 0.f, bF = 0.f, bG = 0.f, bO = 0.f;
  if (u < 200) {
    bI = ldraw(braw, u, f);
    bF = ldraw(braw, 200 + u, f);
    bG = ldraw(braw, 400 + u, f);
    bO = ldraw(braw, 600 + u, f);
  }

  if (tid < 256) hsh[tid] = (_Float16)0.0f;   // zero all quarters incl. pads
  float creg = 0.0f, hreg = 0.0f;
  __syncthreads();

  // --- length tree-reduce ---
  for (int off = 128; off > 0; off >>= 1) {
    if (tid < off) lensh[tid] += lensh[tid + off];
    __syncthreads();
  }
  const int len = lensh[0];   // in [128, 256]

  const unsigned short* gp = (const unsigned short*)Gpre + dir * 800;
  const size_t gbase = (size_t)row * T;
  const uix4* hvp = (const uix4*)((const char*)hsh + kq * 128);
  const int hwrite = (u / 50) * 64 + (u % 50);  // quarter-padded h index

  #pragma unroll 1
  for (int tt = 0; tt < len; ++tt) {
    const int t = dir ? (len - 1 - tt) : tt;
    const size_t goff = (gbase + t) * 1600;
    // prefetch gate pre-activations (consumed in the reduce phase)
    unsigned short qI = 0, qF = 0, qG = 0, qO = 0;
    if (u < 200) {
      qI = gp[goff + u];
      qF = gp[goff + 200 + u];
      qG = gp[goff + 400 + u];
      qO = gp[goff + 600 + u];
    }

    // --- h plane: 7 broadcast b128 reads of this k-quarter ---
    uix4 hb[7];
    #pragma unroll
    for (int i = 0; i < 7; ++i) hb[i] = hvp[i];

    // --- dot phase: fp16 dot2, f32 accumulate ---
    float a0 = 0.f, a1 = 0.f, a2 = 0.f, a3 = 0.f, a4 = 0.f, a5 = 0.f;
    #pragma unroll
    for (int p = 0; p < 25; ++p) {
      half2v h2 = ash2(hb[p >> 2][p & 3]);
      a0 = __builtin_amdgcn_fdot2(ash2(w[0][p]), h2, a0, false);
      a1 = __builtin_amdgcn_fdot2(ash2(w[1][p]), h2, a1, false);
      a2 = __builtin_amdgcn_fdot2(ash2(w[2][p]), h2, a2, false);
      a3 = __builtin_amdgcn_fdot2(ash2(w[3][p]), h2, a3, false);
      a4 = __builtin_amdgcn_fdot2(ash2(w[4][p]), h2, a4, false);
      a5 = __builtin_amdgcn_fdot2(ash2(w[5][p]), h2, a5, false);
    }
    const int pb = kq * 804;
    parts[pb + gs]        = a0;
    parts[pb + 128 + gs]  = a1;
    parts[pb + 256 + gs]  = a2;
    parts[pb + 384 + gs]  = a3;
    parts[pb + 512 + gs]  = a4;
    parts[pb + 640 + gs]  = a5;
    if (tail) {
      float a6 = 0.f;
      #pragma unroll
      for (int p = 0; p < 25; ++p)
        a6 = __builtin_amdgcn_fdot2(ash2(wt[p]), ash2(hb[p >> 2][p & 3]), a6, false);
      parts[pb + 672 + gs] = a6;   // gate 768+(gs-96)
    }
    __syncthreads();

    // --- reduce + nonlinearity (threads 0..199); no pads inside [0,len) ---
    if (u < 200) {
      float gi = parts[u]       + parts[804 + u]       + parts[1608 + u]       + parts[2412 + u]       + bI + bfr2f(qI);
      float gf = parts[200 + u] + parts[804 + 200 + u] + parts[1608 + 200 + u] + parts[2412 + 200 + u] + bF + bfr2f(qF);
      float gg = parts[400 + u] + parts[804 + 400 + u] + parts[1608 + 400 + u] + parts[2412 + 400 + u] + bG + bfr2f(qG);
      float go = parts[600 + u] + parts[804 + 600 + u] + parts[1608 + 600 + u] + parts[2412 + 600 + u] + bO + bfr2f(qO);
      float si = sigm(gi), sf = sigm(gf), so = sigm(go);
      float cn = sf * creg + si * tanh_f(gg);
      float hn = so * tanh_f(cn);
      creg = cn;
      hreg = hn;
      hsh[hwrite] = (_Float16)hn;
      out[((size_t)row * T + t) * ostride + dir * H + u] = __float2bfloat16(hn);
    }
    __syncthreads();
  }

  if (final_h != nullptr && u < 200) {
    // glob_h = [hb1 | hf1]: backward dir -> cols 0..199, forward -> 200..399
    int col = dir ? u : (H + u);
    final_h[(size_t)row * 400 + col] = hreg;
  }
}

// ---------------------------------------------------------------------------
// Span sums v2: chunked (t-chunk x d-octet) with bf16x8 row loads.
// Threads: tc = tid>>6 (t-chunk of 64), dv = tid&63 (d-octet, active < 50).
// Flag loads are wave-uniform (scalar); rows loaded only on span hits.
__global__ __launch_bounds__(256) void span_sum(
    const __hip_bfloat16* __restrict__ rnn,   // [B][T][400]
    const int* __restrict__ masks,
    const int* __restrict__ subj_pos,
    const int* __restrict__ obj_pos,
    float* __restrict__ obj_h,   // [B][400]
    float* __restrict__ subj_h)  // [B][400]
{
  int b = blockIdx.x;
  int tc = threadIdx.x >> 6;
  int dv = threadIdx.x & 63;
  __shared__ float aS[4][400];
  __shared__ float aO[4][400];

  float ss[8] = {}, so[8] = {};
  if (dv < 50) {
    for (int t = tc * 64; t < tc * 64 + 64; ++t) {
      int m = masks[b * T + t];
      int fs = (subj_pos[b * T + t] + m) == 0;
      int fo = (obj_pos[b * T + t] + m) == 0;
      if (fs | fo) {
        uix4 v = *(const uix4*)(rnn + ((size_t)b * T + t) * 400 + dv * 8);
        #pragma unroll
        for (int j = 0; j < 4; ++j) {
          float lo = bfr2f((unsigned short)(v[j] & 0xFFFF));
          float hi = bfr2f((unsigned short)(v[j] >> 16));
          if (fs) { ss[2 * j] += lo; ss[2 * j + 1] += hi; }
          if (fo) { so[2 * j] += lo; so[2 * j + 1] += hi; }
        }
      }
    }
    #pragma unroll
    for (int k = 0; k < 8; ++k) {
      aS[tc][dv * 8 + k] = ss[k];
      aO[tc][dv * 8 + k] = so[k];
    }
  }
  __syncthreads();
  for (int d = threadIdx.x; d < 400; d += 256) {
    subj_h[(size_t)b * 400 + d] = aS[0][d] + aS[1][d] + aS[2][d] + aS[3][d];
    obj_h[(size_t)b * 400 + d]  = aO[0][d] + aO[1][d] + aO[2][d] + aO[3][d];
  }
}

// ---------------------------------------------------------------------------
// Single-query attention pooling v2 (restored — round-11's fused v3 was
// null-to-negative: RNN is L3-resident so the 3x re-reads were cheap, while
// fusion halved block-parallelism). grid = 3*128 (qi = blk>>7, b = blk&127).
__global__ __launch_bounds__(256) void attn_pool_k(
    const float* __restrict__ qbuf,           // [3][B][400]
    const __hip_bfloat16* __restrict__ rnn,   // [B][T][400]
    const int* __restrict__ masks,
    float* __restrict__ outp)                 // [3][B][400]
{
  int b = blockIdx.x & 127;
  int qi = blockIdx.x >> 7;
  __shared__ float qs[400];
  __shared__ float ps[256];
  __shared__ float red[256];
  __shared__ float acc4[4][400];
  const float* q = qbuf + ((size_t)qi * B + b) * 400;
  for (int d = threadIdx.x; d < 400; d += 256) qs[d] = q[d];
  __syncthreads();

  int t = threadIdx.x;
  const uix4* kvv = (const uix4*)(rnn + ((size_t)b * T + t) * 400);
  float s = 0.f;
  #pragma unroll 5
  for (int i = 0; i < 50; ++i) {
    uix4 v = kvv[i];
    #pragma unroll
    for (int j = 0; j < 4; ++j) {
      s += bfr2f((unsigned short)(v[j] & 0xFFFF)) * qs[8 * i + 2 * j];
      s += bfr2f((unsigned short)(v[j] >> 16))    * qs[8 * i + 2 * j + 1];
    }
  }
  s *= 0.05f;  // 1/sqrt(400)
  if (masks[b * T + t] != 0) s = -1e9f;

  red[t] = s;
  __syncthreads();
  for (int off = 128; off > 0; off >>= 1) {
    if (t < off) red[t] = fmaxf(red[t], red[t + off]);
    __syncthreads();
  }
  float mx = red[0];
  __syncthreads();
  float e = expf(s - mx);
  red[t] = e;
  __syncthreads();
  for (int off = 128; off > 0; off >>= 1) {
    if (t < off) red[t] += red[t + off];
    __syncthreads();
  }
  float inv = 1.0f / red[0];
  ps[t] = e * inv;
  __syncthreads();

  // --- phase 2: out[d] = sum_t ps[t] * rnn[t][d], chunked ---
  int tc = threadIdx.x >> 6;
  int dv = threadIdx.x & 63;
  float a[8] = {};
  if (dv < 50) {
    for (int t2 = tc * 64; t2 < tc * 64 + 64; ++t2) {
      float wgt = ps[t2];              // wave-uniform (LDS broadcast)
      if (wgt != 0.f) {
        uix4 v = *(const uix4*)(rnn + ((size_t)b * T + t2) * 400 + dv * 8);
        #pragma unroll
        for (int j = 0; j < 4; ++j) {
          a[2 * j]     += wgt * bfr2f((unsigned short)(v[j] & 0xFFFF));
          a[2 * j + 1] += wgt * bfr2f((unsigned short)(v[j] >> 16));
        }
      }
    }
    #pragma unroll
    for (int k = 0; k < 8; ++k) acc4[tc][dv * 8 + k] = a[k];
  }
  __syncthreads();
  for (int d = threadIdx.x; d < 400; d += 256)
    outp[((size_t)qi * B + b) * 400 + d] =
        acc4[0][d] + acc4[1][d] + acc4[2][d] + acc4[3][d];
}

// ---------------------------------------------------------------------------
// Head — reads all weights raw (flag-dispatched), writes bf16 or f32 per flag
__global__ __launch_bounds__(256) void final_head(
    const float* __restrict__ attn,   // [3][B][400]: 0=obj,1=subj,2=glob
    const void* __restrict__ wo_w, const void* __restrict__ wo_b,
    const void* __restrict__ ws_w, const void* __restrict__ ws_b,
    const void* __restrict__ wg_w, const void* __restrict__ wg_b,
    const void* __restrict__ cls_w, const void* __restrict__ cls_b,
    void* __restrict__ outp,          // [B][2]
    const int* __restrict__ flag)
{
  int b = blockIdx.x;
  int f = *flag;
  __shared__ float hs[H];
  int j = threadIdx.x;
  if (j < H) {
    float acc = ldraw(wo_b, j, f) + ldraw(ws_b, j, f) + ldraw(wg_b, j, f);
    const float* oa = attn + ((size_t)0 * B + b) * 400;
    const float* sa = attn + ((size_t)1 * B + b) * 400;
    const float* ga = attn + ((size_t)2 * B + b) * 400;
    for (int d = 0; d < 400; ++d) {
      acc += oa[d] * ldraw(wo_w, (size_t)j * 400 + d, f);
      acc += sa[d] * ldraw(ws_w, (size_t)j * 400 + d, f);
      acc += ga[d] * ldraw(wg_w, (size_t)j * 400 + d, f);
    }
    hs[j] = fmaxf(acc, 0.0f);
  }
  __syncthreads();
  if (j < 2) {
    float a = ldraw(cls_b, j, f);
    for (int k = 0; k < H; ++k)
      a += hs[k] * ldraw(cls_w, (size_t)j * H + k, f);
    if (f) ((float*)outp)[b * 2 + j] = a;
    else   ((__hip_bfloat16*)outp)[b * 2 + j] = __float2bfloat16(a);
  }
}

// ---------------------------------------------------------------------------
// Workspace layout (bytes)
constexpr size_t O_X0   = 0;            // 32768*384*2  = 25165824
constexpr size_t O_X1   = 25165824;     // 32768*416*2  = 27262976
constexpr size_t O_GPRE = 52428800;     // 32768*1600*2 = 104857600
constexpr size_t O_RNN  = 157286400;    // 32768*400*2  = 26214400
constexpr size_t O_WIH0 = 183500800;    // 1600*384*2   = 1228800
constexpr size_t O_WIH1 = 184729600;    // 1600*416*2   = 1331200
constexpr size_t O_WPK  = 186060800;    // 4*800*100*4  = 1280000
constexpr size_t O_Q    = 187340800;    // 3*128*400*4  = 614400
constexpr size_t O_ATT  = 187955200;    // 614400
constexpr size_t O_FLAG = 188569600;    // 256

extern "C" void kernel_launch(void* const* d_in, const int* in_sizes, int n_in,
                              void* d_out, int out_size, void* d_ws, size_t ws_size,
                              hipStream_t stream) {
  (void)in_sizes; (void)n_in; (void)out_size; (void)ws_size;

  const int* words = (const int*)d_in[0];
  const int* masks = (const int*)d_in[1];
  const int* pos   = (const int*)d_in[2];
  const int* ner   = (const int*)d_in[3];
  const int* subj  = (const int*)d_in[4];
  const int* obj   = (const int*)d_in[5];
  const void* emb_w = d_in[6];
  const void* pos_w = d_in[7];
  const void* ner_w = d_in[8];
  const void* wih[4]  = {d_in[9],  d_in[12], d_in[15], d_in[18]};
  const void* whh[4]  = {d_in[10], d_in[13], d_in[16], d_in[19]};
  const void* bias[4] = {d_in[11], d_in[14], d_in[17], d_in[20]};
  const void* wo_w = d_in[21]; const void* wo_b = d_in[22];
  const void* ws_w = d_in[23]; const void* ws_b = d_in[24];
  const void* wg_w = d_in[25]; const void* wg_b = d_in[26];
  const void* cls_w = d_in[27]; const void* cls_b = d_in[28];

  char* ws = (char*)d_ws;
  __hip_bfloat16* X0   = (__hip_bfloat16*)(ws + O_X0);
  __hip_bfloat16* X1   = (__hip_bfloat16*)(ws + O_X1);
  __hip_bfloat16* Gpre = (__hip_bfloat16*)(ws + O_GPRE);   // [BT][1600]
  __hip_bfloat16* RNN  = (__hip_bfloat16*)(ws + O_RNN);
  __hip_bfloat16* wih0p = (__hip_bfloat16*)(ws + O_WIH0);  // [1600][384]
  __hip_bfloat16* wih1p = (__hip_bfloat16*)(ws + O_WIH1);  // [1600][416]
  unsigned* Wpack = (unsigned*)(ws + O_WPK);               // [4][800][100]
  float* qbuf = (float*)(ws + O_Q);    // [3][B][400]: obj, subj, glob
  float* attb = (float*)(ws + O_ATT);  // [3][B][400]
  int* flag = (int*)(ws + O_FLAG);

  // --- dtype detect + merged weight prep (pack + both pad-copies) ---
  detect_dtype<<<1, 256, 0, stream>>>((const unsigned short*)emb_w, flag);
  prep_weights<<<4450, 256, 0, stream>>>(
      whh[0], whh[1], whh[2], whh[3], Wpack,
      wih[0], wih[1], wih0p, wih[2], wih[3], wih1p, flag);

  // --- embedding (8 tokens/block) + merged output-buffer zero fill ---
  embed_kernel<<<BT / 8, 256, 0, stream>>>(words, pos, ner, emb_w, pos_w, ner_w,
                                           X0, flag);
  fill_zero2<<<2048, 256, 0, stream>>>((uix4*)X1, (size_t)BT * K1P * 2 / 16,
                                       (uix4*)RNN, (size_t)BT * 400 * 2 / 16);

  dim3 ggrid(BT / 128, 13);  // 128x128 tiles, N = 1600 (both dirs fused)

  // --- layer 0 ---
  gemm_bt<<<ggrid, 256, 0, stream>>>(X0, wih0p, Gpre, 1600, K0P);
  lstm_row<<<256, 512, 0, stream>>>(Gpre, Wpack, bias[0], bias[1], masks,
                                    X1, K1P, nullptr, flag);

  // --- layer 1 ---
  gemm_bt<<<ggrid, 256, 0, stream>>>(X1, wih1p, Gpre, 1600, K1P);
  float* qglob = qbuf + (size_t)2 * B * 400;
  lstm_row<<<256, 512, 0, stream>>>(Gpre, Wpack + (size_t)2 * G4 * 100,
                                    bias[2], bias[3], masks,
                                    RNN, 400, qglob, flag);

  // --- span sums (obj -> slot0, subj -> slot1) ---
  span_sum<<<B, 256, 0, stream>>>(RNN, masks, subj, obj,
                                  qbuf, qbuf + (size_t)B * 400);

  // --- attention pooling (3 queries, v2) ---
  attn_pool_k<<<3 * B, 256, 0, stream>>>(qbuf, RNN, masks, attb);

  // --- head (raw weights) ---
  final_head<<<B, 256, 0, stream>>>(attb, wo_w, wo_b, ws_w, ws_b, wg_w, wg_b,
                                    cls_w, cls_b, d_out, flag);
}

// Round 13
// 1119.176 us; speedup vs baseline: 1.0419x; 1.0217x over previous
//
#include <hip/hip_runtime.h>
#include <hip/hip_bf16.h>
#include <math.h>

// Problem constants
constexpr int B = 128;
constexpr int T = 256;
constexpr int H = 200;       // hidden
constexpr int G4 = 800;      // 4*H
constexpr int BT = B * T;    // 32768
constexpr int K0 = 360, K0P = 384;   // layer0 input dim, padded to %32
constexpr int K1 = 400, K1P = 416;   // layer1 input dim, padded to %32

typedef __bf16 bf16x8 __attribute__((ext_vector_type(8)));
typedef float f32x4 __attribute__((ext_vector_type(4)));
typedef _Float16 half2v __attribute__((ext_vector_type(2)));
typedef unsigned uix4 __attribute__((ext_vector_type(4)));

__device__ __forceinline__ float bfr2f(unsigned short u) {
  union { unsigned int i; float f; } x;
  x.i = ((unsigned int)u) << 16;
  return x.f;
}
__device__ __forceinline__ unsigned short f2hu(float f) {
  _Float16 h = (_Float16)f;
  return *(unsigned short*)&h;
}
__device__ __forceinline__ half2v ash2(unsigned u) {
  union { unsigned v; half2v h; } x;
  x.v = u;
  return x.h;
}
__device__ __forceinline__ float sigm(float x) {
  return 1.0f / (1.0f + __expf(-x));
}
__device__ __forceinline__ float tanh_f(float x) {
  float e = __expf(2.0f * x);
  return (e - 1.0f) / (e + 1.0f);
}
// flag-dispatched raw load of a "float" input (f32 or bf16 storage)
__device__ __forceinline__ float ldraw(const void* p, size_t i, int f) {
  return f ? ((const float*)p)[i] : bfr2f(((const unsigned short*)p)[i]);
}

// ---------------------------------------------------------------------------
// Dtype detector (f32 vs bf16 storage of float inputs); see round-2 notes.
__global__ void detect_dtype(const unsigned short* __restrict__ raw,
                             int* __restrict__ flag) {
  __shared__ int cnt[256];
  int c = 0;
  for (int j = 0; j < 32; ++j) {
    unsigned short u = raw[1024 + threadIdx.x * 32 + j];
    int e = (u >> 7) & 0xFF;
    if (e >= 0xC0) ++c;
  }
  cnt[threadIdx.x] = c;
  __syncthreads();
  for (int off = 128; off > 0; off >>= 1) {
    if (threadIdx.x < off) cnt[threadIdx.x] += cnt[threadIdx.x + off];
    __syncthreads();
  }
  if (threadIdx.x == 0) *flag = (cnt[0] > 16) ? 1 : 0;
}

// ---------------------------------------------------------------------------
// Merged embedding + zero-fill (one launch; round-13 gap trim).
//  blocks [0,4096):      embed 8 tokens/block into X0
//  blocks [4096,6144):   grid-stride zero-fill of X1 and RNN
__global__ __launch_bounds__(256) void embed_fill(
    const int* __restrict__ words,
    const int* __restrict__ pos,
    const int* __restrict__ ner,
    const void* __restrict__ emb_w,
    const void* __restrict__ pos_w,
    const void* __restrict__ ner_w,
    __hip_bfloat16* __restrict__ X0,
    uix4* __restrict__ z0, size_t n0,   // X1 region (uix4 count)
    uix4* __restrict__ z1, size_t n1,   // RNN region
    const int* __restrict__ flag) {
  if (blockIdx.x < 4096) {
    int bt = blockIdx.x * 8 + (threadIdx.x >> 5);
    int j0 = threadIdx.x & 31;
    int f = *flag;
    int w = words[bt], p = pos[bt], nr = ner[bt];
    for (int j = j0; j < K0P; j += 32) {
      float v;
      if (j < 300)       v = ldraw(emb_w, (size_t)w * 300 + j, f);
      else if (j < 330)  v = ldraw(pos_w, (size_t)p * 30 + (j - 300), f);
      else if (j < 360)  v = ldraw(ner_w, (size_t)nr * 30 + (j - 330), f);
      else               v = 0.0f;
      X0[(size_t)bt * K0P + j] = __float2bfloat16(v);
    }
  } else {
    size_t i = (size_t)(blockIdx.x - 4096) * 256 + threadIdx.x;
    size_t stride = (size_t)2048 * 256;
    uix4 z = {0u, 0u, 0u, 0u};
    size_t nt = n0 + n1;
    for (; i < nt; i += stride) {
      if (i < n0) z0[i] = z;
      else        z1[i - n0] = z;
    }
  }
}

// ---------------------------------------------------------------------------
// Merged weight prep (one launch replaces pack_whh4 + 2x pad_copy2):
//  blocks [0,1250):    pack all 4 W_hh into fp16 k-pair dwords
//  blocks [1250,2850): pad-copy W_ih layer0 -> [1600][K0P] bf16
//  blocks [2850,4450): pad-copy W_ih layer1 -> [1600][K1P] bf16
__global__ __launch_bounds__(256) void prep_weights(
    const void* __restrict__ whh0, const void* __restrict__ whh1,
    const void* __restrict__ whh2, const void* __restrict__ whh3,
    unsigned* __restrict__ wpack,
    const void* __restrict__ wih0f, const void* __restrict__ wih0b,
    __hip_bfloat16* __restrict__ wih0p,
    const void* __restrict__ wih1f, const void* __restrict__ wih1b,
    __hip_bfloat16* __restrict__ wih1p,
    const int* __restrict__ flag) {
  int blk = blockIdx.x;
  int f = *flag;
  if (blk < 1250) {
    int idx = blk * 256 + threadIdx.x;  // 4*800*100 = 320000
    if (idx >= 4 * G4 * 100) return;
    int m = idx / (G4 * 100);
    int loc = idx - m * (G4 * 100);
    const void* src = (m == 0) ? whh0 : (m == 1) ? whh1 : (m == 2) ? whh2 : whh3;
    int n = loc / 100, p = loc - n * 100;
    float lo_f = ldraw(src, (size_t)n * 200 + 2 * p, f);
    float hi_f = ldraw(src, (size_t)n * 200 + 2 * p + 1, f);
    wpack[idx] = (unsigned)f2hu(lo_f) | ((unsigned)f2hu(hi_f) << 16);
  } else if (blk < 2850) {
    int r = blk - 1250;  // 0..1599
    const void* src = (r < G4) ? wih0f : wih0b;
    int rr = (r < G4) ? r : r - G4;
    for (int j = threadIdx.x; j < K0P; j += 256) {
      float v = (j < K0) ? ldraw(src, (size_t)rr * K0 + j, f) : 0.0f;
      wih0p[(size_t)r * K0P + j] = __float2bfloat16(v);
    }
  } else {
    int r = blk - 2850;  // 0..1599
    const void* src = (r < G4) ? wih1f : wih1b;
    int rr = (r < G4) ? r : r - G4;
    for (int j = threadIdx.x; j < K1P; j += 256) {
      float v = (j < K1) ? ldraw(src, (size_t)rr * K1 + j, f) : 0.0f;
      wih1p[(size_t)r * K1P + j] = __float2bfloat16(v);
    }
  }
}

// ---------------------------------------------------------------------------
// MFMA GEMM v3.1: LDS-staged 128x128 tile, BK=64, double-buffered, XOR-
// swizzled, reg-staged (verified round 9) + XCD-aware A-panel decode:
// 1-D grid 3328; x = blk&7 is the XCD under round-robin dispatch, so panel
// m_tile = x + 8*(j/13) puts all 13 n-tiles sharing one A-panel on the SAME
// XCD, temporally adjacent -> A fetched once into that XCD's L2, hit 12x
// (previous (256,13) grid launched A-sharers 256 blocks apart -> panel
// evicted, A re-fetched up to 13x). Pure index remap; bijection verified
// (3328 = 8*416, 416 = 13*32).
__global__ __launch_bounds__(256) void gemm_bt(
    const __hip_bfloat16* __restrict__ A,
    const __hip_bfloat16* __restrict__ Bm,
    __hip_bfloat16* __restrict__ C,
    int N, int Kp) {
  const int tid = threadIdx.x;
  const int lane = tid & 63;
  const int wave = tid >> 6;           // 0..3
  const int l15 = lane & 15, quad = lane >> 4;
  const int wr = wave & 1, wc = wave >> 1;   // 2x2 wave grid, 64x64 each

  // XCD-aware decode: 13 n-tiles of one m-panel land on one XCD, adjacent.
  const int blk = blockIdx.x;
  const int x = blk & 7, j = blk >> 3;
  const int m0 = (x + 8 * (j / 13)) * 128;
  const int n0 = (j % 13) * 128;

  // [2 bufs][128 rows][8 chunks of 8 bf16] per matrix = 32 KB each
  __shared__ __align__(16) __hip_bfloat16 Ab[2][128 * 64];
  __shared__ __align__(16) __hip_bfloat16 Bb[2][128 * 64];

  f32x4 acc[4][4] = {};

  const int nk = (Kp + 63) >> 6;   // 384->6, 416->7

  // Per-thread staging chunks: j=0..3 -> A chunk c=tid+j*256 (c in [0,1024)),
  // j=4..7 -> B chunk c-1024. chunk c: row=c>>3, pos p=c&7, data qd=p^(row&7).
  uix4 st[8];
  auto stage_issue = [&](int kt) {
    const int k0 = kt << 6;
    #pragma unroll
    for (int jj = 0; jj < 8; ++jj) {
      int c = tid + (jj & 3) * 256;
      int row = c >> 3, p = c & 7;
      int qd = p ^ (row & 7);
      int kcol = k0 + qd * 8;
      uix4 z = {0u, 0u, 0u, 0u};
      if (kcol + 8 <= Kp) {
        if (jj < 4) {
          st[jj] = *(const uix4*)(A + (size_t)(m0 + row) * Kp + kcol);
        } else {
          int br = n0 + row; if (br > N - 1) br = N - 1;
          st[jj] = *(const uix4*)(Bm + (size_t)br * Kp + kcol);
        }
      } else {
        st[jj] = z;
      }
    }
  };
  auto stage_write = [&](int buf) {
    #pragma unroll
    for (int jj = 0; jj < 8; ++jj) {
      int c = tid + (jj & 3) * 256;
      if (jj < 4) *(uix4*)((char*)&Ab[buf][0] + c * 16) = st[jj];
      else        *(uix4*)((char*)&Bb[buf][0] + c * 16) = st[jj];
    }
  };

  // prologue: tile 0 into buf 0
  stage_issue(0);
  stage_write(0);
  __syncthreads();

  for (int kt = 0; kt < nk; ++kt) {
    const int buf = kt & 1;
    if (kt + 1 < nk) stage_issue(kt + 1);   // loads in flight over compute

    #pragma unroll
    for (int k32 = 0; k32 < 2; ++k32) {
      bf16x8 a[4], b[4];
      #pragma unroll
      for (int mi = 0; mi < 4; ++mi) {
        int row = wr * 64 + mi * 16 + l15;
        int p = (k32 * 4 + quad) ^ (row & 7);
        a[mi] = *(const bf16x8*)((const char*)&Ab[buf][0] + (row * 8 + p) * 16);
      }
      #pragma unroll
      for (int ni = 0; ni < 4; ++ni) {
        int row = wc * 64 + ni * 16 + l15;
        int p = (k32 * 4 + quad) ^ (row & 7);
        b[ni] = *(const bf16x8*)((const char*)&Bb[buf][0] + (row * 8 + p) * 16);
      }
      #pragma unroll
      for (int mi = 0; mi < 4; ++mi)
        #pragma unroll
        for (int ni = 0; ni < 4; ++ni)
          acc[mi][ni] = __builtin_amdgcn_mfma_f32_16x16x32_bf16(
              a[mi], b[ni], acc[mi][ni], 0, 0, 0);
    }

    if (kt + 1 < nk) stage_write((kt + 1) & 1);  // vmcnt waits inserted here
    __syncthreads();
  }

  #pragma unroll
  for (int mi = 0; mi < 4; ++mi)
    #pragma unroll
    for (int ni = 0; ni < 4; ++ni)
      #pragma unroll
      for (int r = 0; r < 4; ++r) {
        int row = m0 + wr * 64 + mi * 16 + quad * 4 + r;
        int col = n0 + wc * 64 + ni * 16 + l15;
        if (col < N)
          C[(size_t)row * N + col] = __float2bfloat16(acc[mi][ni][r]);
      }
}

// ---------------------------------------------------------------------------
// LSTM recurrence v7 (verbatim, best verified: 357-365 µs/dispatch; rounds
// 2-8 established this structure's floor).
__global__ __launch_bounds__(512, 2) void lstm_row(
    const __hip_bfloat16* __restrict__ Gpre,   // [B*T][1600]  x@W_ih^T (no bias)
    const unsigned* __restrict__ Wpack,        // [2][800][100] packed fp16 k-pairs
    const void* __restrict__ bias_f_raw,       // [800] raw
    const void* __restrict__ bias_b_raw,       // [800] raw
    const int* __restrict__ masks,             // [B][T], 1 = pad
    __hip_bfloat16* __restrict__ out,          // [B][T][ostride] (pre-zeroed)
    int ostride,
    float* __restrict__ final_h,               // [B][400] = [hb | hf], or nullptr
    const int* __restrict__ flag)
{
  const int tid = threadIdx.x;
  const int dir = blockIdx.x >> 7;
  const int row = blockIdx.x & 127;
  const int wave = tid >> 6;
  const int lane = tid & 63;
  const int kq = wave & 3;                    // k-quarter, wave-uniform
  const int gs = ((wave >> 2) << 6) | lane;   // 0..127
  const bool tail = (gs >= 96);               // handles gates 768..799

  __shared__ __align__(16) _Float16 hsh[256];  // 4 quarters x 64 halfs
  __shared__ float parts[4 * 804];             // [kq][gate(+4)], 12864 B
  __shared__ int lensh[256];                   // length reduce scratch
  __shared__ int bigbuf[21504];                // 86016 B: [0:3232)=tail W
                                               // (stride 101); rest pads LDS
                                               // >80KB so 1 block/CU

  const unsigned* wb = Wpack + (size_t)dir * G4 * 100;

  // --- stage tail-gate weights (768..799), stride 101 ---
  for (int i = tid; i < 3200; i += 512) {
    int g = i / 100, c = i - g * 100;
    bigbuf[g * 101 + c] = (int)wb[(768 + g) * 100 + c];
  }
  // --- per-row length: count of keep tokens (pads are a contiguous tail) ---
  if (tid < 256) lensh[tid] = (masks[row * T + tid] == 0) ? 1 : 0;

  // --- register weights: 150 dwords/thread, compile-time indices ---
  unsigned w[6][25];
  {
    const unsigned* s = wb + gs * 100 + kq * 25;
    #pragma unroll
    for (int j = 0; j < 6; ++j)
      #pragma unroll
      for (int p = 0; p < 25; ++p)
        w[j][p] = s[12800 * j + p];
  }
  const unsigned* wt = (const unsigned*)&bigbuf[(gs - 96) * 101 + kq * 25];

  // --- reduce-thread constants (u = hidden unit) ---
  const int u = tid;
  const int f = *flag;
  const void* braw = dir ? bias_b_raw : bias_f_raw;
  float bI = 0.f, bF = 0.f, bG = 0.f, bO = 0.f;
  if (u < 200) {
    bI = ldraw(braw, u, f);
    bF = ldraw(braw, 200 + u, f);
    bG = ldraw(braw, 400 + u, f);
    bO = ldraw(braw, 600 + u, f);
  }

  if (tid < 256) hsh[tid] = (_Float16)0.0f;   // zero all quarters incl. pads
  float creg = 0.0f, hreg = 0.0f;
  __syncthreads();

  // --- length tree-reduce ---
  for (int off = 128; off > 0; off >>= 1) {
    if (tid < off) lensh[tid] += lensh[tid + off];
    __syncthreads();
  }
  const int len = lensh[0];   // in [128, 256]

  const unsigned short* gp = (const unsigned short*)Gpre + dir * 800;
  const size_t gbase = (size_t)row * T;
  const uix4* hvp = (const uix4*)((const char*)hsh + kq * 128);
  const int hwrite = (u / 50) * 64 + (u % 50);  // quarter-padded h index

  #pragma unroll 1
  for (int tt = 0; tt < len; ++tt) {
    const int t = dir ? (len - 1 - tt) : tt;
    const size_t goff = (gbase + t) * 1600;
    // prefetch gate pre-activations (consumed in the reduce phase)
    unsigned short qI = 0, qF = 0, qG = 0, qO = 0;
    if (u < 200) {
      qI = gp[goff + u];
      qF = gp[goff + 200 + u];
      qG = gp[goff + 400 + u];
      qO = gp[goff + 600 + u];
    }

    // --- h plane: 7 broadcast b128 reads of this k-quarter ---
    uix4 hb[7];
    #pragma unroll
    for (int i = 0; i < 7; ++i) hb[i] = hvp[i];

    // --- dot phase: fp16 dot2, f32 accumulate ---
    float a0 = 0.f, a1 = 0.f, a2 = 0.f, a3 = 0.f, a4 = 0.f, a5 = 0.f;
    #pragma unroll
    for (int p = 0; p < 25; ++p) {
      half2v h2 = ash2(hb[p >> 2][p & 3]);
      a0 = __builtin_amdgcn_fdot2(ash2(w[0][p]), h2, a0, false);
      a1 = __builtin_amdgcn_fdot2(ash2(w[1][p]), h2, a1, false);
      a2 = __builtin_amdgcn_fdot2(ash2(w[2][p]), h2, a2, false);
      a3 = __builtin_amdgcn_fdot2(ash2(w[3][p]), h2, a3, false);
      a4 = __builtin_amdgcn_fdot2(ash2(w[4][p]), h2, a4, false);
      a5 = __builtin_amdgcn_fdot2(ash2(w[5][p]), h2, a5, false);
    }
    const int pb = kq * 804;
    parts[pb + gs]        = a0;
    parts[pb + 128 + gs]  = a1;
    parts[pb + 256 + gs]  = a2;
    parts[pb + 384 + gs]  = a3;
    parts[pb + 512 + gs]  = a4;
    parts[pb + 640 + gs]  = a5;
    if (tail) {
      float a6 = 0.f;
      #pragma unroll
      for (int p = 0; p < 25; ++p)
        a6 = __builtin_amdgcn_fdot2(ash2(wt[p]), ash2(hb[p >> 2][p & 3]), a6, false);
      parts[pb + 672 + gs] = a6;   // gate 768+(gs-96)
    }
    __syncthreads();

    // --- reduce + nonlinearity (threads 0..199); no pads inside [0,len) ---
    if (u < 200) {
      float gi = parts[u]       + parts[804 + u]       + parts[1608 + u]       + parts[2412 + u]       + bI + bfr2f(qI);
      float gf = parts[200 + u] + parts[804 + 200 + u] + parts[1608 + 200 + u] + parts[2412 + 200 + u] + bF + bfr2f(qF);
      float gg = parts[400 + u] + parts[804 + 400 + u] + parts[1608 + 400 + u] + parts[2412 + 400 + u] + bG + bfr2f(qG);
      float go = parts[600 + u] + parts[804 + 600 + u] + parts[1608 + 600 + u] + parts[2412 + 600 + u] + bO + bfr2f(qO);
      float si = sigm(gi), sf = sigm(gf), so = sigm(go);
      float cn = sf * creg + si * tanh_f(gg);
      float hn = so * tanh_f(cn);
      creg = cn;
      hreg = hn;
      hsh[hwrite] = (_Float16)hn;
      out[((size_t)row * T + t) * ostride + dir * H + u] = __float2bfloat16(hn);
    }
    __syncthreads();
  }

  if (final_h != nullptr && u < 200) {
    // glob_h = [hb1 | hf1]: backward dir -> cols 0..199, forward -> 200..399
    int col = dir ? u : (H + u);
    final_h[(size_t)row * 400 + col] = hreg;
  }
}

// ---------------------------------------------------------------------------
// Span sums v2: chunked (t-chunk x d-octet) with bf16x8 row loads.
// Threads: tc = tid>>6 (t-chunk of 64), dv = tid&63 (d-octet, active < 50).
// Flag loads are wave-uniform (scalar); rows loaded only on span hits.
__global__ __launch_bounds__(256) void span_sum(
    const __hip_bfloat16* __restrict__ rnn,   // [B][T][400]
    const int* __restrict__ masks,
    const int* __restrict__ subj_pos,
    const int* __restrict__ obj_pos,
    float* __restrict__ obj_h,   // [B][400]
    float* __restrict__ subj_h)  // [B][400]
{
  int b = blockIdx.x;
  int tc = threadIdx.x >> 6;
  int dv = threadIdx.x & 63;
  __shared__ float aS[4][400];
  __shared__ float aO[4][400];

  float ss[8] = {}, so[8] = {};
  if (dv < 50) {
    for (int t = tc * 64; t < tc * 64 + 64; ++t) {
      int m = masks[b * T + t];
      int fs = (subj_pos[b * T + t] + m) == 0;
      int fo = (obj_pos[b * T + t] + m) == 0;
      if (fs | fo) {
        uix4 v = *(const uix4*)(rnn + ((size_t)b * T + t) * 400 + dv * 8);
        #pragma unroll
        for (int j = 0; j < 4; ++j) {
          float lo = bfr2f((unsigned short)(v[j] & 0xFFFF));
          float hi = bfr2f((unsigned short)(v[j] >> 16));
          if (fs) { ss[2 * j] += lo; ss[2 * j + 1] += hi; }
          if (fo) { so[2 * j] += lo; so[2 * j + 1] += hi; }
        }
      }
    }
    #pragma unroll
    for (int k = 0; k < 8; ++k) {
      aS[tc][dv * 8 + k] = ss[k];
      aO[tc][dv * 8 + k] = so[k];
    }
  }
  __syncthreads();
  for (int d = threadIdx.x; d < 400; d += 256) {
    subj_h[(size_t)b * 400 + d] = aS[0][d] + aS[1][d] + aS[2][d] + aS[3][d];
    obj_h[(size_t)b * 400 + d]  = aO[0][d] + aO[1][d] + aO[2][d] + aO[3][d];
  }
}

// ---------------------------------------------------------------------------
// Single-query attention pooling v2 (verified; round-11 fusion regressed).
// grid = 3*128 (qi = blk>>7, b = blk&127).
__global__ __launch_bounds__(256) void attn_pool_k(
    const float* __restrict__ qbuf,           // [3][B][400]
    const __hip_bfloat16* __restrict__ rnn,   // [B][T][400]
    const int* __restrict__ masks,
    float* __restrict__ outp)                 // [3][B][400]
{
  int b = blockIdx.x & 127;
  int qi = blockIdx.x >> 7;
  __shared__ float qs[400];
  __shared__ float ps[256];
  __shared__ float red[256];
  __shared__ float acc4[4][400];
  const float* q = qbuf + ((size_t)qi * B + b) * 400;
  for (int d = threadIdx.x; d < 400; d += 256) qs[d] = q[d];
  __syncthreads();

  int t = threadIdx.x;
  const uix4* kvv = (const uix4*)(rnn + ((size_t)b * T + t) * 400);
  float s = 0.f;
  #pragma unroll 5
  for (int i = 0; i < 50; ++i) {
    uix4 v = kvv[i];
    #pragma unroll
    for (int j = 0; j < 4; ++j) {
      s += bfr2f((unsigned short)(v[j] & 0xFFFF)) * qs[8 * i + 2 * j];
      s += bfr2f((unsigned short)(v[j] >> 16))    * qs[8 * i + 2 * j + 1];
    }
  }
  s *= 0.05f;  // 1/sqrt(400)
  if (masks[b * T + t] != 0) s = -1e9f;

  red[t] = s;
  __syncthreads();
  for (int off = 128; off > 0; off >>= 1) {
    if (t < off) red[t] = fmaxf(red[t], red[t + off]);
    __syncthreads();
  }
  float mx = red[0];
  __syncthreads();
  float e = expf(s - mx);
  red[t] = e;
  __syncthreads();
  for (int off = 128; off > 0; off >>= 1) {
    if (t < off) red[t] += red[t + off];
    __syncthreads();
  }
  float inv = 1.0f / red[0];
  ps[t] = e * inv;
  __syncthreads();

  // --- phase 2: out[d] = sum_t ps[t] * rnn[t][d], chunked ---
  int tc = threadIdx.x >> 6;
  int dv = threadIdx.x & 63;
  float a[8] = {};
  if (dv < 50) {
    for (int t2 = tc * 64; t2 < tc * 64 + 64; ++t2) {
      float wgt = ps[t2];              // wave-uniform (LDS broadcast)
      if (wgt != 0.f) {
        uix4 v = *(const uix4*)(rnn + ((size_t)b * T + t2) * 400 + dv * 8);
        #pragma unroll
        for (int j = 0; j < 4; ++j) {
          a[2 * j]     += wgt * bfr2f((unsigned short)(v[j] & 0xFFFF));
          a[2 * j + 1] += wgt * bfr2f((unsigned short)(v[j] >> 16));
        }
      }
    }
    #pragma unroll
    for (int k = 0; k < 8; ++k) acc4[tc][dv * 8 + k] = a[k];
  }
  __syncthreads();
  for (int d = threadIdx.x; d < 400; d += 256)
    outp[((size_t)qi * B + b) * 400 + d] =
        acc4[0][d] + acc4[1][d] + acc4[2][d] + acc4[3][d];
}

// ---------------------------------------------------------------------------
// Head — reads all weights raw (flag-dispatched), writes bf16 or f32 per flag
__global__ __launch_bounds__(256) void final_head(
    const float* __restrict__ attn,   // [3][B][400]: 0=obj,1=subj,2=glob
    const void* __restrict__ wo_w, const void* __restrict__ wo_b,
    const void* __restrict__ ws_w, const void* __restrict__ ws_b,
    const void* __restrict__ wg_w, const void* __restrict__ wg_b,
    const void* __restrict__ cls_w, const void* __restrict__ cls_b,
    void* __restrict__ outp,          // [B][2]
    const int* __restrict__ flag)
{
  int b = blockIdx.x;
  int f = *flag;
  __shared__ float hs[H];
  int j = threadIdx.x;
  if (j < H) {
    float acc = ldraw(wo_b, j, f) + ldraw(ws_b, j, f) + ldraw(wg_b, j, f);
    const float* oa = attn + ((size_t)0 * B + b) * 400;
    const float* sa = attn + ((size_t)1 * B + b) * 400;
    const float* ga = attn + ((size_t)2 * B + b) * 400;
    for (int d = 0; d < 400; ++d) {
      acc += oa[d] * ldraw(wo_w, (size_t)j * 400 + d, f);
      acc += sa[d] * ldraw(ws_w, (size_t)j * 400 + d, f);
      acc += ga[d] * ldraw(wg_w, (size_t)j * 400 + d, f);
    }
    hs[j] = fmaxf(acc, 0.0f);
  }
  __syncthreads();
  if (j < 2) {
    float a = ldraw(cls_b, j, f);
    for (int k = 0; k < H; ++k)
      a += hs[k] * ldraw(cls_w, (size_t)j * H + k, f);
    if (f) ((float*)outp)[b * 2 + j] = a;
    else   ((__hip_bfloat16*)outp)[b * 2 + j] = __float2bfloat16(a);
  }
}

// ---------------------------------------------------------------------------
// Workspace layout (bytes)
constexpr size_t O_X0   = 0;            // 32768*384*2  = 25165824
constexpr size_t O_X1   = 25165824;     // 32768*416*2  = 27262976
constexpr size_t O_GPRE = 52428800;     // 32768*1600*2 = 104857600
constexpr size_t O_RNN  = 157286400;    // 32768*400*2  = 26214400
constexpr size_t O_WIH0 = 183500800;    // 1600*384*2   = 1228800
constexpr size_t O_WIH1 = 184729600;    // 1600*416*2   = 1331200
constexpr size_t O_WPK  = 186060800;    // 4*800*100*4  = 1280000
constexpr size_t O_Q    = 187340800;    // 3*128*400*4  = 614400
constexpr size_t O_ATT  = 187955200;    // 614400
constexpr size_t O_FLAG = 188569600;    // 256

extern "C" void kernel_launch(void* const* d_in, const int* in_sizes, int n_in,
                              void* d_out, int out_size, void* d_ws, size_t ws_size,
                              hipStream_t stream) {
  (void)in_sizes; (void)n_in; (void)out_size; (void)ws_size;

  const int* words = (const int*)d_in[0];
  const int* masks = (const int*)d_in[1];
  const int* pos   = (const int*)d_in[2];
  const int* ner   = (const int*)d_in[3];
  const int* subj  = (const int*)d_in[4];
  const int* obj   = (const int*)d_in[5];
  const void* emb_w = d_in[6];
  const void* pos_w = d_in[7];
  const void* ner_w = d_in[8];
  const void* wih[4]  = {d_in[9],  d_in[12], d_in[15], d_in[18]};
  const void* whh[4]  = {d_in[10], d_in[13], d_in[16], d_in[19]};
  const void* bias[4] = {d_in[11], d_in[14], d_in[17], d_in[20]};
  const void* wo_w = d_in[21]; const void* wo_b = d_in[22];
  const void* ws_w = d_in[23]; const void* ws_b = d_in[24];
  const void* wg_w = d_in[25]; const void* wg_b = d_in[26];
  const void* cls_w = d_in[27]; const void* cls_b = d_in[28];

  char* ws = (char*)d_ws;
  __hip_bfloat16* X0   = (__hip_bfloat16*)(ws + O_X0);
  __hip_bfloat16* X1   = (__hip_bfloat16*)(ws + O_X1);
  __hip_bfloat16* Gpre = (__hip_bfloat16*)(ws + O_GPRE);   // [BT][1600]
  __hip_bfloat16* RNN  = (__hip_bfloat16*)(ws + O_RNN);
  __hip_bfloat16* wih0p = (__hip_bfloat16*)(ws + O_WIH0);  // [1600][384]
  __hip_bfloat16* wih1p = (__hip_bfloat16*)(ws + O_WIH1);  // [1600][416]
  unsigned* Wpack = (unsigned*)(ws + O_WPK);               // [4][800][100]
  float* qbuf = (float*)(ws + O_Q);    // [3][B][400]: obj, subj, glob
  float* attb = (float*)(ws + O_ATT);  // [3][B][400]
  int* flag = (int*)(ws + O_FLAG);

  // --- dtype detect + merged weight prep (pack + both pad-copies) ---
  detect_dtype<<<1, 256, 0, stream>>>((const unsigned short*)emb_w, flag);
  prep_weights<<<4450, 256, 0, stream>>>(
      whh[0], whh[1], whh[2], whh[3], Wpack,
      wih[0], wih[1], wih0p, wih[2], wih[3], wih1p, flag);

  // --- merged embedding (8 tokens/block) + zero fill of X1/RNN ---
  embed_fill<<<6144, 256, 0, stream>>>(words, pos, ner, emb_w, pos_w, ner_w,
                                       X0,
                                       (uix4*)X1, (size_t)BT * K1P * 2 / 16,
                                       (uix4*)RNN, (size_t)BT * 400 * 2 / 16,
                                       flag);

  const int ggrid = (BT / 128) * 13;   // 3328, XCD-aware decode in-kernel

  // --- layer 0 ---
  gemm_bt<<<ggrid, 256, 0, stream>>>(X0, wih0p, Gpre, 1600, K0P);
  lstm_row<<<256, 512, 0, stream>>>(Gpre, Wpack, bias[0], bias[1], masks,
                                    X1, K1P, nullptr, flag);

  // --- layer 1 ---
  gemm_bt<<<ggrid, 256, 0, stream>>>(X1, wih1p, Gpre, 1600, K1P);
  float* qglob = qbuf + (size_t)2 * B * 400;
  lstm_row<<<256, 512, 0, stream>>>(Gpre, Wpack + (size_t)2 * G4 * 100,
                                    bias[2], bias[3], masks,
                                    RNN, 400, qglob, flag);

  // --- span sums (obj -> slot0, subj -> slot1) ---
  span_sum<<<B, 256, 0, stream>>>(RNN, masks, subj, obj,
                                  qbuf, qbuf + (size_t)B * 400);

  // --- attention pooling (3 queries, v2) ---
  attn_pool_k<<<3 * B, 256, 0, stream>>>(qbuf, RNN, masks, attb);

  // --- head (raw weights) ---
  final_head<<<B, 256, 0, stream>>>(attb, wo_w, wo_b, ws_w, ws_b, wg_w, wg_b,
                                    cls_w, cls_b, d_out, flag);
}

// Round 14
// 1116.257 us; speedup vs baseline: 1.0446x; 1.0026x over previous
//
#include <hip/hip_runtime.h>
#include <hip/hip_bf16.h>
#include <math.h>

// Problem constants
constexpr int B = 128;
constexpr int T = 256;
constexpr int H = 200;       // hidden
constexpr int G4 = 800;      // 4*H
constexpr int BT = B * T;    // 32768
constexpr int K0 = 360, K0P = 384;   // layer0 input dim, padded to %32
constexpr int K1 = 400, K1P = 416;   // layer1 input dim, padded to %32

typedef __bf16 bf16x8 __attribute__((ext_vector_type(8)));
typedef float f32x4 __attribute__((ext_vector_type(4)));
typedef _Float16 half2v __attribute__((ext_vector_type(2)));
typedef unsigned uix4 __attribute__((ext_vector_type(4)));

__device__ __forceinline__ float bfr2f(unsigned short u) {
  union { unsigned int i; float f; } x;
  x.i = ((unsigned int)u) << 16;
  return x.f;
}
__device__ __forceinline__ unsigned short f2hu(float f) {
  _Float16 h = (_Float16)f;
  return *(unsigned short*)&h;
}
__device__ __forceinline__ half2v ash2(unsigned u) {
  union { unsigned v; half2v h; } x;
  x.v = u;
  return x.h;
}
__device__ __forceinline__ float sigm(float x) {
  return 1.0f / (1.0f + __expf(-x));
}
__device__ __forceinline__ float tanh_f(float x) {
  float e = __expf(2.0f * x);
  return (e - 1.0f) / (e + 1.0f);
}
// flag-dispatched raw load of a "float" input (f32 or bf16 storage)
__device__ __forceinline__ float ldraw(const void* p, size_t i, int f) {
  return f ? ((const float*)p)[i] : bfr2f(((const unsigned short*)p)[i]);
}

// Direct global->LDS 16B copy (gfx950). LDS dest computed per-lane but linear
// in lane with stride 16 (= transfer size), matching HW's wave-uniform-base +
// lane*16 write; swizzle lives in the per-lane GLOBAL source (m173 pattern).
__device__ __forceinline__ void glds16(const void* g, void* l) {
  __builtin_amdgcn_global_load_lds(
      (const __attribute__((address_space(1))) unsigned int*)g,
      (__attribute__((address_space(3))) unsigned int*)l, 16, 0, 0);
}

// ---------------------------------------------------------------------------
// Dtype detector (f32 vs bf16 storage of float inputs); see round-2 notes.
__global__ void detect_dtype(const unsigned short* __restrict__ raw,
                             int* __restrict__ flag) {
  __shared__ int cnt[256];
  int c = 0;
  for (int j = 0; j < 32; ++j) {
    unsigned short u = raw[1024 + threadIdx.x * 32 + j];
    int e = (u >> 7) & 0xFF;
    if (e >= 0xC0) ++c;
  }
  cnt[threadIdx.x] = c;
  __syncthreads();
  for (int off = 128; off > 0; off >>= 1) {
    if (threadIdx.x < off) cnt[threadIdx.x] += cnt[threadIdx.x + off];
    __syncthreads();
  }
  if (threadIdx.x == 0) *flag = (cnt[0] > 16) ? 1 : 0;
}

// ---------------------------------------------------------------------------
// Merged prep (one launch replaces weight-prep + embed + zero-fill; round-14
// gap trim, 10 -> 8 dispatches):
//  blocks [0,1250):      pack all 4 W_hh into fp16 k-pair dwords
//  blocks [1250,2850):   pad-copy W_ih layer0 -> [1600][K0P] bf16
//  blocks [2850,4450):   pad-copy W_ih layer1 -> [1600][K1P] bf16
//  blocks [4450,8546):   embed 8 tokens/block into X0
//  blocks [8546,10594):  grid-stride zero-fill of X1 and RNN
__global__ __launch_bounds__(256) void prep_all(
    const void* __restrict__ whh0, const void* __restrict__ whh1,
    const void* __restrict__ whh2, const void* __restrict__ whh3,
    unsigned* __restrict__ wpack,
    const void* __restrict__ wih0f, const void* __restrict__ wih0b,
    __hip_bfloat16* __restrict__ wih0p,
    const void* __restrict__ wih1f, const void* __restrict__ wih1b,
    __hip_bfloat16* __restrict__ wih1p,
    const int* __restrict__ words,
    const int* __restrict__ pos,
    const int* __restrict__ ner,
    const void* __restrict__ emb_w,
    const void* __restrict__ pos_w,
    const void* __restrict__ ner_w,
    __hip_bfloat16* __restrict__ X0,
    uix4* __restrict__ z0, size_t n0,   // X1 region (uix4 count)
    uix4* __restrict__ z1, size_t n1,   // RNN region
    const int* __restrict__ flag) {
  int blk = blockIdx.x;
  int f = *flag;
  if (blk < 1250) {
    int idx = blk * 256 + threadIdx.x;  // 4*800*100 = 320000
    if (idx >= 4 * G4 * 100) return;
    int m = idx / (G4 * 100);
    int loc = idx - m * (G4 * 100);
    const void* src = (m == 0) ? whh0 : (m == 1) ? whh1 : (m == 2) ? whh2 : whh3;
    int n = loc / 100, p = loc - n * 100;
    float lo_f = ldraw(src, (size_t)n * 200 + 2 * p, f);
    float hi_f = ldraw(src, (size_t)n * 200 + 2 * p + 1, f);
    wpack[idx] = (unsigned)f2hu(lo_f) | ((unsigned)f2hu(hi_f) << 16);
  } else if (blk < 2850) {
    int r = blk - 1250;  // 0..1599
    const void* src = (r < G4) ? wih0f : wih0b;
    int rr = (r < G4) ? r : r - G4;
    for (int j = threadIdx.x; j < K0P; j += 256) {
      float v = (j < K0) ? ldraw(src, (size_t)rr * K0 + j, f) : 0.0f;
      wih0p[(size_t)r * K0P + j] = __float2bfloat16(v);
    }
  } else if (blk < 4450) {
    int r = blk - 2850;  // 0..1599
    const void* src = (r < G4) ? wih1f : wih1b;
    int rr = (r < G4) ? r : r - G4;
    for (int j = threadIdx.x; j < K1P; j += 256) {
      float v = (j < K1) ? ldraw(src, (size_t)rr * K1 + j, f) : 0.0f;
      wih1p[(size_t)r * K1P + j] = __float2bfloat16(v);
    }
  } else if (blk < 8546) {
    int bt = (blk - 4450) * 8 + (threadIdx.x >> 5);
    int j0 = threadIdx.x & 31;
    int w = words[bt], p = pos[bt], nr = ner[bt];
    for (int j = j0; j < K0P; j += 32) {
      float v;
      if (j < 300)       v = ldraw(emb_w, (size_t)w * 300 + j, f);
      else if (j < 330)  v = ldraw(pos_w, (size_t)p * 30 + (j - 300), f);
      else if (j < 360)  v = ldraw(ner_w, (size_t)nr * 30 + (j - 330), f);
      else               v = 0.0f;
      X0[(size_t)bt * K0P + j] = __float2bfloat16(v);
    }
  } else {
    size_t i = (size_t)(blk - 8546) * 256 + threadIdx.x;
    size_t stride = (size_t)2048 * 256;
    uix4 z = {0u, 0u, 0u, 0u};
    size_t nt = n0 + n1;
    for (; i < nt; i += stride) {
      if (i < n0) z0[i] = z;
      else        z1[i - n0] = z;
    }
  }
}

// ---------------------------------------------------------------------------
// MFMA GEMM v4.1: LDS-staged 128x128 tile, BK=64, double-buffered, XOR-
// swizzled, XCD-aware decode (verified round 13), with staging via
// global_load_lds (no VGPR round-trip; m151: +35% at this tile). LDS chunk
// layout is linear in tid (dest = base + lane*16), XOR swizzle qd=p^(row&7)
// applied to the per-lane GLOBAL source. K-tail (Kp=416: one 32-wide tile)
// keeps reg-staged zero fill (glds can't deposit zeros OOB).
// [Retry of round-10's v4: that bench died at container level, same error as
//  rounds 5/6 which later proved infra (round-8 ran that kernel fine).
//  Decision rule: a second container failure implicates glds permanently.]
__global__ __launch_bounds__(256) void gemm_bt(
    const __hip_bfloat16* __restrict__ A,
    const __hip_bfloat16* __restrict__ Bm,
    __hip_bfloat16* __restrict__ C,
    int N, int Kp) {
  const int tid = threadIdx.x;
  const int lane = tid & 63;
  const int wave = tid >> 6;           // 0..3
  const int l15 = lane & 15, quad = lane >> 4;
  const int wr = wave & 1, wc = wave >> 1;   // 2x2 wave grid, 64x64 each

  // XCD-aware decode: 13 n-tiles of one m-panel land on one XCD, adjacent.
  const int blk = blockIdx.x;
  const int x = blk & 7, j = blk >> 3;
  const int m0 = (x + 8 * (j / 13)) * 128;
  const int n0 = (j % 13) * 128;

  // [2 bufs][128 rows][8 chunks of 8 bf16] per matrix = 32 KB each
  __shared__ __align__(16) __hip_bfloat16 Ab[2][128 * 64];
  __shared__ __align__(16) __hip_bfloat16 Bb[2][128 * 64];

  f32x4 acc[4][4] = {};

  const int nk_full = Kp >> 6;                    // 384->6, 416->6
  const int nk = nk_full + ((Kp & 63) ? 1 : 0);   // 384->6, 416->7

  for (int kt = 0; kt <= nk; ++kt) {
    // --- stage tile kt into buf kt&1 (kt==0 staged before any compute) ---
    if (kt < nk) {
      const int buf = kt & 1;
      if (kt < nk_full) {
        // full tile: direct global->LDS DMA, swizzle in global source addr
        const int k0 = kt << 6;
        #pragma unroll
        for (int jj = 0; jj < 4; ++jj) {
          int c = tid + jj * 256;               // chunk id, linear in tid
          int row = c >> 3, p = c & 7;
          int qd = p ^ (row & 7);
          glds16(A + (size_t)(m0 + row) * Kp + k0 + qd * 8,
                 (char*)&Ab[buf][0] + c * 16);
          int br = n0 + row; if (br > N - 1) br = N - 1;
          glds16(Bm + (size_t)br * Kp + k0 + qd * 8,
                 (char*)&Bb[buf][0] + c * 16);
        }
      } else {
        // tail tile (Kp%64 != 0): reg-staged with zero fill past Kp
        const int k0 = nk_full << 6;
        #pragma unroll
        for (int jj = 0; jj < 8; ++jj) {
          int c = tid + (jj & 3) * 256;
          int row = c >> 3, p = c & 7;
          int qd = p ^ (row & 7);
          int kcol = k0 + qd * 8;
          uix4 v = {0u, 0u, 0u, 0u};
          if (kcol + 8 <= Kp) {
            if (jj < 4) {
              v = *(const uix4*)(A + (size_t)(m0 + row) * Kp + kcol);
            } else {
              int br = n0 + row; if (br > N - 1) br = N - 1;
              v = *(const uix4*)(Bm + (size_t)br * Kp + kcol);
            }
          }
          if (jj < 4) *(uix4*)((char*)&Ab[buf][0] + c * 16) = v;
          else        *(uix4*)((char*)&Bb[buf][0] + c * 16) = v;
        }
      }
    }

    // --- compute tile kt-1 from buf (kt-1)&1 (staged last iteration) ---
    if (kt > 0) {
      const int buf = (kt - 1) & 1;
      #pragma unroll
      for (int k32 = 0; k32 < 2; ++k32) {
        bf16x8 a[4], b[4];
        #pragma unroll
        for (int mi = 0; mi < 4; ++mi) {
          int row = wr * 64 + mi * 16 + l15;
          int p = (k32 * 4 + quad) ^ (row & 7);
          a[mi] = *(const bf16x8*)((const char*)&Ab[buf][0] + (row * 8 + p) * 16);
        }
        #pragma unroll
        for (int ni = 0; ni < 4; ++ni) {
          int row = wc * 64 + ni * 16 + l15;
          int p = (k32 * 4 + quad) ^ (row & 7);
          b[ni] = *(const bf16x8*)((const char*)&Bb[buf][0] + (row * 8 + p) * 16);
        }
        #pragma unroll
        for (int mi = 0; mi < 4; ++mi)
          #pragma unroll
          for (int ni = 0; ni < 4; ++ni)
            acc[mi][ni] = __builtin_amdgcn_mfma_f32_16x16x32_bf16(
                a[mi], b[ni], acc[mi][ni], 0, 0, 0);
      }
    }

    __syncthreads();   // drains vmcnt/lgkm: tile kt landed, buf kt-1 consumed
  }

  #pragma unroll
  for (int mi = 0; mi < 4; ++mi)
    #pragma unroll
    for (int ni = 0; ni < 4; ++ni)
      #pragma unroll
      for (int r = 0; r < 4; ++r) {
        int row = m0 + wr * 64 + mi * 16 + quad * 4 + r;
        int col = n0 + wc * 64 + ni * 16 + l15;
        if (col < N)
          C[(size_t)row * N + col] = __float2bfloat16(acc[mi][ni][r]);
      }
}

// ---------------------------------------------------------------------------
// LSTM recurrence v7 (verbatim, best verified: 357-365 µs/dispatch; rounds
// 2-8 established this structure's floor).
__global__ __launch_bounds__(512, 2) void lstm_row(
    const __hip_bfloat16* __restrict__ Gpre,   // [B*T][1600]  x@W_ih^T (no bias)
    const unsigned* __restrict__ Wpack,        // [2][800][100] packed fp16 k-pairs
    const void* __restrict__ bias_f_raw,       // [800] raw
    const void* __restrict__ bias_b_raw,       // [800] raw
    const int* __restrict__ masks,             // [B][T], 1 = pad
    __hip_bfloat16* __restrict__ out,          // [B][T][ostride] (pre-zeroed)
    int ostride,
    float* __restrict__ final_h,               // [B][400] = [hb | hf], or nullptr
    const int* __restrict__ flag)
{
  const int tid = threadIdx.x;
  const int dir = blockIdx.x >> 7;
  const int row = blockIdx.x & 127;
  const int wave = tid >> 6;
  const int lane = tid & 63;
  const int kq = wave & 3;                    // k-quarter, wave-uniform
  const int gs = ((wave >> 2) << 6) | lane;   // 0..127
  const bool tail = (gs >= 96);               // handles gates 768..799

  __shared__ __align__(16) _Float16 hsh[256];  // 4 quarters x 64 halfs
  __shared__ float parts[4 * 804];             // [kq][gate(+4)], 12864 B
  __shared__ int lensh[256];                   // length reduce scratch
  __shared__ int bigbuf[21504];                // 86016 B: [0:3232)=tail W
                                               // (stride 101); rest pads LDS
                                               // >80KB so 1 block/CU

  const unsigned* wb = Wpack + (size_t)dir * G4 * 100;

  // --- stage tail-gate weights (768..799), stride 101 ---
  for (int i = tid; i < 3200; i += 512) {
    int g = i / 100, c = i - g * 100;
    bigbuf[g * 101 + c] = (int)wb[(768 + g) * 100 + c];
  }
  // --- per-row length: count of keep tokens (pads are a contiguous tail) ---
  if (tid < 256) lensh[tid] = (masks[row * T + tid] == 0) ? 1 : 0;

  // --- register weights: 150 dwords/thread, compile-time indices ---
  unsigned w[6][25];
  {
    const unsigned* s = wb + gs * 100 + kq * 25;
    #pragma unroll
    for (int j = 0; j < 6; ++j)
      #pragma unroll
      for (int p = 0; p < 25; ++p)
        w[j][p] = s[12800 * j + p];
  }
  const unsigned* wt = (const unsigned*)&bigbuf[(gs - 96) * 101 + kq * 25];

  // --- reduce-thread constants (u = hidden unit) ---
  const int u = tid;
  const int f = *flag;
  const void* braw = dir ? bias_b_raw : bias_f_raw;
  float bI = 0.f, bF = 0.f, bG = 0.f, bO = 0.f;
  if (u < 200) {
    bI = ldraw(braw, u, f);
    bF = ldraw(braw, 200 + u, f);
    bG = ldraw(braw, 400 + u, f);
    bO = ldraw(braw, 600 + u, f);
  }

  if (tid < 256) hsh[tid] = (_Float16)0.0f;   // zero all quarters incl. pads
  float creg = 0.0f, hreg = 0.0f;
  __syncthreads();

  // --- length tree-reduce ---
  for (int off = 128; off > 0; off >>= 1) {
    if (tid < off) lensh[tid] += lensh[tid + off];
    __syncthreads();
  }
  const int len = lensh[0];   // in [128, 256]

  const unsigned short* gp = (const unsigned short*)Gpre + dir * 800;
  const size_t gbase = (size_t)row * T;
  const uix4* hvp = (const uix4*)((const char*)hsh + kq * 128);
  const int hwrite = (u / 50) * 64 + (u % 50);  // quarter-padded h index

  #pragma unroll 1
  for (int tt = 0; tt < len; ++tt) {
    const int t = dir ? (len - 1 - tt) : tt;
    const size_t goff = (gbase + t) * 1600;
    // prefetch gate pre-activations (consumed in the reduce phase)
    unsigned short qI = 0, qF = 0, qG = 0, qO = 0;
    if (u < 200) {
      qI = gp[goff + u];
      qF = gp[goff + 200 + u];
      qG = gp[goff + 400 + u];
      qO = gp[goff + 600 + u];
    }

    // --- h plane: 7 broadcast b128 reads of this k-quarter ---
    uix4 hb[7];
    #pragma unroll
    for (int i = 0; i < 7; ++i) hb[i] = hvp[i];

    // --- dot phase: fp16 dot2, f32 accumulate ---
    float a0 = 0.f, a1 = 0.f, a2 = 0.f, a3 = 0.f, a4 = 0.f, a5 = 0.f;
    #pragma unroll
    for (int p = 0; p < 25; ++p) {
      half2v h2 = ash2(hb[p >> 2][p & 3]);
      a0 = __builtin_amdgcn_fdot2(ash2(w[0][p]), h2, a0, false);
      a1 = __builtin_amdgcn_fdot2(ash2(w[1][p]), h2, a1, false);
      a2 = __builtin_amdgcn_fdot2(ash2(w[2][p]), h2, a2, false);
      a3 = __builtin_amdgcn_fdot2(ash2(w[3][p]), h2, a3, false);
      a4 = __builtin_amdgcn_fdot2(ash2(w[4][p]), h2, a4, false);
      a5 = __builtin_amdgcn_fdot2(ash2(w[5][p]), h2, a5, false);
    }
    const int pb = kq * 804;
    parts[pb + gs]        = a0;
    parts[pb + 128 + gs]  = a1;
    parts[pb + 256 + gs]  = a2;
    parts[pb + 384 + gs]  = a3;
    parts[pb + 512 + gs]  = a4;
    parts[pb + 640 + gs]  = a5;
    if (tail) {
      float a6 = 0.f;
      #pragma unroll
      for (int p = 0; p < 25; ++p)
        a6 = __builtin_amdgcn_fdot2(ash2(wt[p]), ash2(hb[p >> 2][p & 3]), a6, false);
      parts[pb + 672 + gs] = a6;   // gate 768+(gs-96)
    }
    __syncthreads();

    // --- reduce + nonlinearity (threads 0..199); no pads inside [0,len) ---
    if (u < 200) {
      float gi = parts[u]       + parts[804 + u]       + parts[1608 + u]       + parts[2412 + u]       + bI + bfr2f(qI);
      float gf = parts[200 + u] + parts[804 + 200 + u] + parts[1608 + 200 + u] + parts[2412 + 200 + u] + bF + bfr2f(qF);
      float gg = parts[400 + u] + parts[804 + 400 + u] + parts[1608 + 400 + u] + parts[2412 + 400 + u] + bG + bfr2f(qG);
      float go = parts[600 + u] + parts[804 + 600 + u] + parts[1608 + 600 + u] + parts[2412 + 600 + u] + bO + bfr2f(qO);
      float si = sigm(gi), sf = sigm(gf), so = sigm(go);
      float cn = sf * creg + si * tanh_f(gg);
      float hn = so * tanh_f(cn);
      creg = cn;
      hreg = hn;
      hsh[hwrite] = (_Float16)hn;
      out[((size_t)row * T + t) * ostride + dir * H + u] = __float2bfloat16(hn);
    }
    __syncthreads();
  }

  if (final_h != nullptr && u < 200) {
    // glob_h = [hb1 | hf1]: backward dir -> cols 0..199, forward -> 200..399
    int col = dir ? u : (H + u);
    final_h[(size_t)row * 400 + col] = hreg;
  }
}

// ---------------------------------------------------------------------------
// Span sums v2: chunked (t-chunk x d-octet) with bf16x8 row loads.
// Threads: tc = tid>>6 (t-chunk of 64), dv = tid&63 (d-octet, active < 50).
// Flag loads are wave-uniform (scalar); rows loaded only on span hits.
__global__ __launch_bounds__(256) void span_sum(
    const __hip_bfloat16* __restrict__ rnn,   // [B][T][400]
    const int* __restrict__ masks,
    const int* __restrict__ subj_pos,
    const int* __restrict__ obj_pos,
    float* __restrict__ obj_h,   // [B][400]
    float* __restrict__ subj_h)  // [B][400]
{
  int b = blockIdx.x;
  int tc = threadIdx.x >> 6;
  int dv = threadIdx.x & 63;
  __shared__ float aS[4][400];
  __shared__ float aO[4][400];

  float ss[8] = {}, so[8] = {};
  if (dv < 50) {
    for (int t = tc * 64; t < tc * 64 + 64; ++t) {
      int m = masks[b * T + t];
      int fs = (subj_pos[b * T + t] + m) == 0;
      int fo = (obj_pos[b * T + t] + m) == 0;
      if (fs | fo) {
        uix4 v = *(const uix4*)(rnn + ((size_t)b * T + t) * 400 + dv * 8);
        #pragma unroll
        for (int j = 0; j < 4; ++j) {
          float lo = bfr2f((unsigned short)(v[j] & 0xFFFF));
          float hi = bfr2f((unsigned short)(v[j] >> 16));
          if (fs) { ss[2 * j] += lo; ss[2 * j + 1] += hi; }
          if (fo) { so[2 * j] += lo; so[2 * j + 1] += hi; }
        }
      }
    }
    #pragma unroll
    for (int k = 0; k < 8; ++k) {
      aS[tc][dv * 8 + k] = ss[k];
      aO[tc][dv * 8 + k] = so[k];
    }
  }
  __syncthreads();
  for (int d = threadIdx.x; d < 400; d += 256) {
    subj_h[(size_t)b * 400 + d] = aS[0][d] + aS[1][d] + aS[2][d] + aS[3][d];
    obj_h[(size_t)b * 400 + d]  = aO[0][d] + aO[1][d] + aO[2][d] + aO[3][d];
  }
}

// ---------------------------------------------------------------------------
// Single-query attention pooling v2 (verified; round-11 fusion regressed).
// grid = 3*128 (qi = blk>>7, b = blk&127).
__global__ __launch_bounds__(256) void attn_pool_k(
    const float* __restrict__ qbuf,           // [3][B][400]
    const __hip_bfloat16* __restrict__ rnn,   // [B][T][400]
    const int* __restrict__ masks,
    float* __restrict__ outp)                 // [3][B][400]
{
  int b = blockIdx.x & 127;
  int qi = blockIdx.x >> 7;
  __shared__ float qs[400];
  __shared__ float ps[256];
  __shared__ float red[256];
  __shared__ float acc4[4][400];
  const float* q = qbuf + ((size_t)qi * B + b) * 400;
  for (int d = threadIdx.x; d < 400; d += 256) qs[d] = q[d];
  __syncthreads();

  int t = threadIdx.x;
  const uix4* kvv = (const uix4*)(rnn + ((size_t)b * T + t) * 400);
  float s = 0.f;
  #pragma unroll 5
  for (int i = 0; i < 50; ++i) {
    uix4 v = kvv[i];
    #pragma unroll
    for (int j = 0; j < 4; ++j) {
      s += bfr2f((unsigned short)(v[j] & 0xFFFF)) * qs[8 * i + 2 * j];
      s += bfr2f((unsigned short)(v[j] >> 16))    * qs[8 * i + 2 * j + 1];
    }
  }
  s *= 0.05f;  // 1/sqrt(400)
  if (masks[b * T + t] != 0) s = -1e9f;

  red[t] = s;
  __syncthreads();
  for (int off = 128; off > 0; off >>= 1) {
    if (t < off) red[t] = fmaxf(red[t], red[t + off]);
    __syncthreads();
  }
  float mx = red[0];
  __syncthreads();
  float e = expf(s - mx);
  red[t] = e;
  __syncthreads();
  for (int off = 128; off > 0; off >>= 1) {
    if (t < off) red[t] += red[t + off];
    __syncthreads();
  }
  float inv = 1.0f / red[0];
  ps[t] = e * inv;
  __syncthreads();

  // --- phase 2: out[d] = sum_t ps[t] * rnn[t][d], chunked ---
  int tc = threadIdx.x >> 6;
  int dv = threadIdx.x & 63;
  float a[8] = {};
  if (dv < 50) {
    for (int t2 = tc * 64; t2 < tc * 64 + 64; ++t2) {
      float wgt = ps[t2];              // wave-uniform (LDS broadcast)
      if (wgt != 0.f) {
        uix4 v = *(const uix4*)(rnn + ((size_t)b * T + t2) * 400 + dv * 8);
        #pragma unroll
        for (int j = 0; j < 4; ++j) {
          a[2 * j]     += wgt * bfr2f((unsigned short)(v[j] & 0xFFFF));
          a[2 * j + 1] += wgt * bfr2f((unsigned short)(v[j] >> 16));
        }
      }
    }
    #pragma unroll
    for (int k = 0; k < 8; ++k) acc4[tc][dv * 8 + k] = a[k];
  }
  __syncthreads();
  for (int d = threadIdx.x; d < 400; d += 256)
    outp[((size_t)qi * B + b) * 400 + d] =
        acc4[0][d] + acc4[1][d] + acc4[2][d] + acc4[3][d];
}

// ---------------------------------------------------------------------------
// Head — reads all weights raw (flag-dispatched), writes bf16 or f32 per flag
__global__ __launch_bounds__(256) void final_head(
    const float* __restrict__ attn,   // [3][B][400]: 0=obj,1=subj,2=glob
    const void* __restrict__ wo_w, const void* __restrict__ wo_b,
    const void* __restrict__ ws_w, const void* __restrict__ ws_b,
    const void* __restrict__ wg_w, const void* __restrict__ wg_b,
    const void* __restrict__ cls_w, const void* __restrict__ cls_b,
    void* __restrict__ outp,          // [B][2]
    const int* __restrict__ flag)
{
  int b = blockIdx.x;
  int f = *flag;
  __shared__ float hs[H];
  int j = threadIdx.x;
  if (j < H) {
    float acc = ldraw(wo_b, j, f) + ldraw(ws_b, j, f) + ldraw(wg_b, j, f);
    const float* oa = attn + ((size_t)0 * B + b) * 400;
    const float* sa = attn + ((size_t)1 * B + b) * 400;
    const float* ga = attn + ((size_t)2 * B + b) * 400;
    for (int d = 0; d < 400; ++d) {
      acc += oa[d] * ldraw(wo_w, (size_t)j * 400 + d, f);
      acc += sa[d] * ldraw(ws_w, (size_t)j * 400 + d, f);
      acc += ga[d] * ldraw(wg_w, (size_t)j * 400 + d, f);
    }
    hs[j] = fmaxf(acc, 0.0f);
  }
  __syncthreads();
  if (j < 2) {
    float a = ldraw(cls_b, j, f);
    for (int k = 0; k < H; ++k)
      a += hs[k] * ldraw(cls_w, (size_t)j * H + k, f);
    if (f) ((float*)outp)[b * 2 + j] = a;
    else   ((__hip_bfloat16*)outp)[b * 2 + j] = __float2bfloat16(a);
  }
}

// ---------------------------------------------------------------------------
// Workspace layout (bytes)
constexpr size_t O_X0   = 0;            // 32768*384*2  = 25165824
constexpr size_t O_X1   = 25165824;     // 32768*416*2  = 27262976
constexpr size_t O_GPRE = 52428800;     // 32768*1600*2 = 104857600
constexpr size_t O_RNN  = 157286400;    // 32768*400*2  = 26214400
constexpr size_t O_WIH0 = 183500800;    // 1600*384*2   = 1228800
constexpr size_t O_WIH1 = 184729600;    // 1600*416*2   = 1331200
constexpr size_t O_WPK  = 186060800;    // 4*800*100*4  = 1280000
constexpr size_t O_Q    = 187340800;    // 3*128*400*4  = 614400
constexpr size_t O_ATT  = 187955200;    // 614400
constexpr size_t O_FLAG = 188569600;    // 256

extern "C" void kernel_launch(void* const* d_in, const int* in_sizes, int n_in,
                              void* d_out, int out_size, void* d_ws, size_t ws_size,
                              hipStream_t stream) {
  (void)in_sizes; (void)n_in; (void)out_size; (void)ws_size;

  const int* words = (const int*)d_in[0];
  const int* masks = (const int*)d_in[1];
  const int* pos   = (const int*)d_in[2];
  const int* ner   = (const int*)d_in[3];
  const int* subj  = (const int*)d_in[4];
  const int* obj   = (const int*)d_in[5];
  const void* emb_w = d_in[6];
  const void* pos_w = d_in[7];
  const void* ner_w = d_in[8];
  const void* wih[4]  = {d_in[9],  d_in[12], d_in[15], d_in[18]};
  const void* whh[4]  = {d_in[10], d_in[13], d_in[16], d_in[19]};
  const void* bias[4] = {d_in[11], d_in[14], d_in[17], d_in[20]};
  const void* wo_w = d_in[21]; const void* wo_b = d_in[22];
  const void* ws_w = d_in[23]; const void* ws_b = d_in[24];
  const void* wg_w = d_in[25]; const void* wg_b = d_in[26];
  const void* cls_w = d_in[27]; const void* cls_b = d_in[28];

  char* ws = (char*)d_ws;
  __hip_bfloat16* X0   = (__hip_bfloat16*)(ws + O_X0);
  __hip_bfloat16* X1   = (__hip_bfloat16*)(ws + O_X1);
  __hip_bfloat16* Gpre = (__hip_bfloat16*)(ws + O_GPRE);   // [BT][1600]
  __hip_bfloat16* RNN  = (__hip_bfloat16*)(ws + O_RNN);
  __hip_bfloat16* wih0p = (__hip_bfloat16*)(ws + O_WIH0);  // [1600][384]
  __hip_bfloat16* wih1p = (__hip_bfloat16*)(ws + O_WIH1);  // [1600][416]
  unsigned* Wpack = (unsigned*)(ws + O_WPK);               // [4][800][100]
  float* qbuf = (float*)(ws + O_Q);    // [3][B][400]: obj, subj, glob
  float* attb = (float*)(ws + O_ATT);  // [3][B][400]
  int* flag = (int*)(ws + O_FLAG);

  // --- dtype detect + fully-merged prep (weights + embed + zero-fill) ---
  detect_dtype<<<1, 256, 0, stream>>>((const unsigned short*)emb_w, flag);
  prep_all<<<10594, 256, 0, stream>>>(
      whh[0], whh[1], whh[2], whh[3], Wpack,
      wih[0], wih[1], wih0p, wih[2], wih[3], wih1p,
      words, pos, ner, emb_w, pos_w, ner_w, X0,
      (uix4*)X1, (size_t)BT * K1P * 2 / 16,
      (uix4*)RNN, (size_t)BT * 400 * 2 / 16,
      flag);

  const int ggrid = (BT / 128) * 13;   // 3328, XCD-aware decode in-kernel

  // --- layer 0 ---
  gemm_bt<<<ggrid, 256, 0, stream>>>(X0, wih0p, Gpre, 1600, K0P);
  lstm_row<<<256, 512, 0, stream>>>(Gpre, Wpack, bias[0], bias[1], masks,
                                    X1, K1P, nullptr, flag);

  // --- layer 1 ---
  gemm_bt<<<ggrid, 256, 0, stream>>>(X1, wih1p, Gpre, 1600, K1P);
  float* qglob = qbuf + (size_t)2 * B * 400;
  lstm_row<<<256, 512, 0, stream>>>(Gpre, Wpack + (size_t)2 * G4 * 100,
                                    bias[2], bias[3], masks,
                                    RNN, 400, qglob, flag);

  // --- span sums (obj -> slot0, subj -> slot1) ---
  span_sum<<<B, 256, 0, stream>>>(RNN, masks, subj, obj,
                                  qbuf, qbuf + (size_t)B * 400);

  // --- attention pooling (3 queries, v2) ---
  attn_pool_k<<<3 * B, 256, 0, stream>>>(qbuf, RNN, masks, attb);

  // --- head (raw weights) ---
  final_head<<<B, 256, 0, stream>>>(attb, wo_w, wo_b, ws_w, ws_b, wg_w, wg_b,
                                    cls_w, cls_b, d_out, flag);
}

// Round 15
// 1108.432 us; speedup vs baseline: 1.0520x; 1.0071x over previous
//
#include <hip/hip_runtime.h>
#include <hip/hip_bf16.h>
#include <math.h>

// Problem constants
constexpr int B = 128;
constexpr int T = 256;
constexpr int H = 200;       // hidden
constexpr int G4 = 800;      // 4*H
constexpr int BT = B * T;    // 32768
constexpr int K0 = 360, K0P = 384;   // layer0 input dim, padded to %32
constexpr int K1 = 400, K1P = 416;   // layer1 input dim, padded to %32

typedef __bf16 bf16x8 __attribute__((ext_vector_type(8)));
typedef float f32x4 __attribute__((ext_vector_type(4)));
typedef _Float16 half2v __attribute__((ext_vector_type(2)));
typedef unsigned uix4 __attribute__((ext_vector_type(4)));

__device__ __forceinline__ float bfr2f(unsigned short u) {
  union { unsigned int i; float f; } x;
  x.i = ((unsigned int)u) << 16;
  return x.f;
}
__device__ __forceinline__ unsigned short f2hu(float f) {
  _Float16 h = (_Float16)f;
  return *(unsigned short*)&h;
}
__device__ __forceinline__ half2v ash2(unsigned u) {
  union { unsigned v; half2v h; } x;
  x.v = u;
  return x.h;
}
__device__ __forceinline__ float sigm(float x) {
  return 1.0f / (1.0f + __expf(-x));
}
__device__ __forceinline__ float tanh_f(float x) {
  float e = __expf(2.0f * x);
  return (e - 1.0f) / (e + 1.0f);
}
// flag-dispatched raw load of a "float" input (f32 or bf16 storage)
__device__ __forceinline__ float ldraw(const void* p, size_t i, int f) {
  return f ? ((const float*)p)[i] : bfr2f(((const unsigned short*)p)[i]);
}

// Direct global->LDS 16B copy (gfx950). LDS dest linear in lane with stride
// 16 (= transfer size) matching HW wave-uniform-base + lane*16; swizzle in
// the per-lane GLOBAL source (m173 pattern). Verified correct in round 14.
__device__ __forceinline__ void glds16(const void* g, void* l) {
  __builtin_amdgcn_global_load_lds(
      (const __attribute__((address_space(1))) unsigned int*)g,
      (__attribute__((address_space(3))) unsigned int*)l, 16, 0, 0);
}

// ---------------------------------------------------------------------------
// Dtype detector (f32 vs bf16 storage of float inputs); see round-2 notes.
__global__ void detect_dtype(const unsigned short* __restrict__ raw,
                             int* __restrict__ flag) {
  __shared__ int cnt[256];
  int c = 0;
  for (int j = 0; j < 32; ++j) {
    unsigned short u = raw[1024 + threadIdx.x * 32 + j];
    int e = (u >> 7) & 0xFF;
    if (e >= 0xC0) ++c;
  }
  cnt[threadIdx.x] = c;
  __syncthreads();
  for (int off = 128; off > 0; off >>= 1) {
    if (threadIdx.x < off) cnt[threadIdx.x] += cnt[threadIdx.x + off];
    __syncthreads();
  }
  if (threadIdx.x == 0) *flag = (cnt[0] > 16) ? 1 : 0;
}

// ---------------------------------------------------------------------------
// Merged prep (weights + embed + zero-fill; verified round 14):
//  blocks [0,1250):      pack all 4 W_hh into fp16 k-pair dwords
//  blocks [1250,2850):   pad-copy W_ih layer0 -> [1600][K0P] bf16
//  blocks [2850,4450):   pad-copy W_ih layer1 -> [1600][K1P] bf16
//  blocks [4450,8546):   embed 8 tokens/block into X0
//  blocks [8546,10594):  grid-stride zero-fill of X1 and RNN
__global__ __launch_bounds__(256) void prep_all(
    const void* __restrict__ whh0, const void* __restrict__ whh1,
    const void* __restrict__ whh2, const void* __restrict__ whh3,
    unsigned* __restrict__ wpack,
    const void* __restrict__ wih0f, const void* __restrict__ wih0b,
    __hip_bfloat16* __restrict__ wih0p,
    const void* __restrict__ wih1f, const void* __restrict__ wih1b,
    __hip_bfloat16* __restrict__ wih1p,
    const int* __restrict__ words,
    const int* __restrict__ pos,
    const int* __restrict__ ner,
    const void* __restrict__ emb_w,
    const void* __restrict__ pos_w,
    const void* __restrict__ ner_w,
    __hip_bfloat16* __restrict__ X0,
    uix4* __restrict__ z0, size_t n0,   // X1 region (uix4 count)
    uix4* __restrict__ z1, size_t n1,   // RNN region
    const int* __restrict__ flag) {
  int blk = blockIdx.x;
  int f = *flag;
  if (blk < 1250) {
    int idx = blk * 256 + threadIdx.x;  // 4*800*100 = 320000
    if (idx >= 4 * G4 * 100) return;
    int m = idx / (G4 * 100);
    int loc = idx - m * (G4 * 100);
    const void* src = (m == 0) ? whh0 : (m == 1) ? whh1 : (m == 2) ? whh2 : whh3;
    int n = loc / 100, p = loc - n * 100;
    float lo_f = ldraw(src, (size_t)n * 200 + 2 * p, f);
    float hi_f = ldraw(src, (size_t)n * 200 + 2 * p + 1, f);
    wpack[idx] = (unsigned)f2hu(lo_f) | ((unsigned)f2hu(hi_f) << 16);
  } else if (blk < 2850) {
    int r = blk - 1250;  // 0..1599
    const void* src = (r < G4) ? wih0f : wih0b;
    int rr = (r < G4) ? r : r - G4;
    for (int j = threadIdx.x; j < K0P; j += 256) {
      float v = (j < K0) ? ldraw(src, (size_t)rr * K0 + j, f) : 0.0f;
      wih0p[(size_t)r * K0P + j] = __float2bfloat16(v);
    }
  } else if (blk < 4450) {
    int r = blk - 2850;  // 0..1599
    const void* src = (r < G4) ? wih1f : wih1b;
    int rr = (r < G4) ? r : r - G4;
    for (int j = threadIdx.x; j < K1P; j += 256) {
      float v = (j < K1) ? ldraw(src, (size_t)rr * K1 + j, f) : 0.0f;
      wih1p[(size_t)r * K1P + j] = __float2bfloat16(v);
    }
  } else if (blk < 8546) {
    int bt = (blk - 4450) * 8 + (threadIdx.x >> 5);
    int j0 = threadIdx.x & 31;
    int w = words[bt], p = pos[bt], nr = ner[bt];
    for (int j = j0; j < K0P; j += 32) {
      float v;
      if (j < 300)       v = ldraw(emb_w, (size_t)w * 300 + j, f);
      else if (j < 330)  v = ldraw(pos_w, (size_t)p * 30 + (j - 300), f);
      else if (j < 360)  v = ldraw(ner_w, (size_t)nr * 30 + (j - 330), f);
      else               v = 0.0f;
      X0[(size_t)bt * K0P + j] = __float2bfloat16(v);
    }
  } else {
    size_t i = (size_t)(blk - 8546) * 256 + threadIdx.x;
    size_t stride = (size_t)2048 * 256;
    uix4 z = {0u, 0u, 0u, 0u};
    size_t nt = n0 + n1;
    for (; i < nt; i += stride) {
      if (i < n0) z0[i] = z;
      else        z1[i - n0] = z;
    }
  }
}

// ---------------------------------------------------------------------------
// MFMA GEMM v5: SINGLE-buffered 128x128 tile, BK=64, glds staging, XOR-
// swizzled, XCD-aware decode. Round-14 post-mortem: glds (the staging lever)
// was neutral -> the kernel is not staging-bound; with nk=6-7 and only ~160
// cyc of MFMA issue per wave per k-iter at 2 blocks/CU, it is bound by
// per-block serialization (barrier + load-return latency). v5 halves LDS
// (64->32 KB) by dropping the double buffer -> 4 blocks/CU; co-resident
// INDEPENDENT blocks (no shared barriers) overlap each other's stage and
// compute phases (m114 wave-level overlap), which intra-block dbuf could
// not. Structure: stage -> barrier -> compute -> barrier. Numerics identical.
__global__ __launch_bounds__(256) void gemm_bt(
    const __hip_bfloat16* __restrict__ A,
    const __hip_bfloat16* __restrict__ Bm,
    __hip_bfloat16* __restrict__ C,
    int N, int Kp) {
  const int tid = threadIdx.x;
  const int lane = tid & 63;
  const int wave = tid >> 6;           // 0..3
  const int l15 = lane & 15, quad = lane >> 4;
  const int wr = wave & 1, wc = wave >> 1;   // 2x2 wave grid, 64x64 each

  // XCD-aware decode: 13 n-tiles of one m-panel land on one XCD, adjacent.
  const int blk = blockIdx.x;
  const int x = blk & 7, j = blk >> 3;
  const int m0 = (x + 8 * (j / 13)) * 128;
  const int n0 = (j % 13) * 128;

  // single buffer: [128 rows][8 chunks of 8 bf16] per matrix = 16 KB each
  __shared__ __align__(16) __hip_bfloat16 Ab[128 * 64];
  __shared__ __align__(16) __hip_bfloat16 Bb[128 * 64];

  f32x4 acc[4][4] = {};

  const int nk_full = Kp >> 6;                    // 384->6, 416->6
  const int nk = nk_full + ((Kp & 63) ? 1 : 0);   // 384->6, 416->7

  for (int kt = 0; kt < nk; ++kt) {
    // --- stage tile kt ---
    if (kt < nk_full) {
      const int k0 = kt << 6;
      #pragma unroll
      for (int jj = 0; jj < 4; ++jj) {
        int c = tid + jj * 256;               // chunk id, linear in tid
        int row = c >> 3, p = c & 7;
        int qd = p ^ (row & 7);
        glds16(A + (size_t)(m0 + row) * Kp + k0 + qd * 8,
               (char*)&Ab[0] + c * 16);
        int br = n0 + row; if (br > N - 1) br = N - 1;
        glds16(Bm + (size_t)br * Kp + k0 + qd * 8,
               (char*)&Bb[0] + c * 16);
      }
    } else {
      // tail tile (Kp%64 != 0): reg-staged with zero fill past Kp
      const int k0 = nk_full << 6;
      #pragma unroll
      for (int jj = 0; jj < 8; ++jj) {
        int c = tid + (jj & 3) * 256;
        int row = c >> 3, p = c & 7;
        int qd = p ^ (row & 7);
        int kcol = k0 + qd * 8;
        uix4 v = {0u, 0u, 0u, 0u};
        if (kcol + 8 <= Kp) {
          if (jj < 4) {
            v = *(const uix4*)(A + (size_t)(m0 + row) * Kp + kcol);
          } else {
            int br = n0 + row; if (br > N - 1) br = N - 1;
            v = *(const uix4*)(Bm + (size_t)br * Kp + kcol);
          }
        }
        if (jj < 4) *(uix4*)((char*)&Ab[0] + c * 16) = v;
        else        *(uix4*)((char*)&Bb[0] + c * 16) = v;
      }
    }
    __syncthreads();   // loads landed (vmcnt+lgkm drained)

    // --- compute tile kt ---
    #pragma unroll
    for (int k32 = 0; k32 < 2; ++k32) {
      bf16x8 a[4], b[4];
      #pragma unroll
      for (int mi = 0; mi < 4; ++mi) {
        int row = wr * 64 + mi * 16 + l15;
        int p = (k32 * 4 + quad) ^ (row & 7);
        a[mi] = *(const bf16x8*)((const char*)&Ab[0] + (row * 8 + p) * 16);
      }
      #pragma unroll
      for (int ni = 0; ni < 4; ++ni) {
        int row = wc * 64 + ni * 16 + l15;
        int p = (k32 * 4 + quad) ^ (row & 7);
        b[ni] = *(const bf16x8*)((const char*)&Bb[0] + (row * 8 + p) * 16);
      }
      #pragma unroll
      for (int mi = 0; mi < 4; ++mi)
        #pragma unroll
        for (int ni = 0; ni < 4; ++ni)
          acc[mi][ni] = __builtin_amdgcn_mfma_f32_16x16x32_bf16(
              a[mi], b[ni], acc[mi][ni], 0, 0, 0);
    }
    __syncthreads();   // ds reads complete before next overwrite
  }

  #pragma unroll
  for (int mi = 0; mi < 4; ++mi)
    #pragma unroll
    for (int ni = 0; ni < 4; ++ni)
      #pragma unroll
      for (int r = 0; r < 4; ++r) {
        int row = m0 + wr * 64 + mi * 16 + quad * 4 + r;
        int col = n0 + wc * 64 + ni * 16 + l15;
        if (col < N)
          C[(size_t)row * N + col] = __float2bfloat16(acc[mi][ni][r]);
      }
}

// ---------------------------------------------------------------------------
// LSTM recurrence v7 (verbatim, best verified: 357-365 µs/dispatch; rounds
// 2-8 established this structure's floor).
__global__ __launch_bounds__(512, 2) void lstm_row(
    const __hip_bfloat16* __restrict__ Gpre,   // [B*T][1600]  x@W_ih^T (no bias)
    const unsigned* __restrict__ Wpack,        // [2][800][100] packed fp16 k-pairs
    const void* __restrict__ bias_f_raw,       // [800] raw
    const void* __restrict__ bias_b_raw,       // [800] raw
    const int* __restrict__ masks,             // [B][T], 1 = pad
    __hip_bfloat16* __restrict__ out,          // [B][T][ostride] (pre-zeroed)
    int ostride,
    float* __restrict__ final_h,               // [B][400] = [hb | hf], or nullptr
    const int* __restrict__ flag)
{
  const int tid = threadIdx.x;
  const int dir = blockIdx.x >> 7;
  const int row = blockIdx.x & 127;
  const int wave = tid >> 6;
  const int lane = tid & 63;
  const int kq = wave & 3;                    // k-quarter, wave-uniform
  const int gs = ((wave >> 2) << 6) | lane;   // 0..127
  const bool tail = (gs >= 96);               // handles gates 768..799

  __shared__ __align__(16) _Float16 hsh[256];  // 4 quarters x 64 halfs
  __shared__ float parts[4 * 804];             // [kq][gate(+4)], 12864 B
  __shared__ int lensh[256];                   // length reduce scratch
  __shared__ int bigbuf[21504];                // 86016 B: [0:3232)=tail W
                                               // (stride 101); rest pads LDS
                                               // >80KB so 1 block/CU

  const unsigned* wb = Wpack + (size_t)dir * G4 * 100;

  // --- stage tail-gate weights (768..799), stride 101 ---
  for (int i = tid; i < 3200; i += 512) {
    int g = i / 100, c = i - g * 100;
    bigbuf[g * 101 + c] = (int)wb[(768 + g) * 100 + c];
  }
  // --- per-row length: count of keep tokens (pads are a contiguous tail) ---
  if (tid < 256) lensh[tid] = (masks[row * T + tid] == 0) ? 1 : 0;

  // --- register weights: 150 dwords/thread, compile-time indices ---
  unsigned w[6][25];
  {
    const unsigned* s = wb + gs * 100 + kq * 25;
    #pragma unroll
    for (int j = 0; j < 6; ++j)
      #pragma unroll
      for (int p = 0; p < 25; ++p)
        w[j][p] = s[12800 * j + p];
  }
  const unsigned* wt = (const unsigned*)&bigbuf[(gs - 96) * 101 + kq * 25];

  // --- reduce-thread constants (u = hidden unit) ---
  const int u = tid;
  const int f = *flag;
  const void* braw = dir ? bias_b_raw : bias_f_raw;
  float bI = 0.f, bF = 0.f, bG = 0.f, bO = 0.f;
  if (u < 200) {
    bI = ldraw(braw, u, f);
    bF = ldraw(braw, 200 + u, f);
    bG = ldraw(braw, 400 + u, f);
    bO = ldraw(braw, 600 + u, f);
  }

  if (tid < 256) hsh[tid] = (_Float16)0.0f;   // zero all quarters incl. pads
  float creg = 0.0f, hreg = 0.0f;
  __syncthreads();

  // --- length tree-reduce ---
  for (int off = 128; off > 0; off >>= 1) {
    if (tid < off) lensh[tid] += lensh[tid + off];
    __syncthreads();
  }
  const int len = lensh[0];   // in [128, 256]

  const unsigned short* gp = (const unsigned short*)Gpre + dir * 800;
  const size_t gbase = (size_t)row * T;
  const uix4* hvp = (const uix4*)((const char*)hsh + kq * 128);
  const int hwrite = (u / 50) * 64 + (u % 50);  // quarter-padded h index

  #pragma unroll 1
  for (int tt = 0; tt < len; ++tt) {
    const int t = dir ? (len - 1 - tt) : tt;
    const size_t goff = (gbase + t) * 1600;
    // prefetch gate pre-activations (consumed in the reduce phase)
    unsigned short qI = 0, qF = 0, qG = 0, qO = 0;
    if (u < 200) {
      qI = gp[goff + u];
      qF = gp[goff + 200 + u];
      qG = gp[goff + 400 + u];
      qO = gp[goff + 600 + u];
    }

    // --- h plane: 7 broadcast b128 reads of this k-quarter ---
    uix4 hb[7];
    #pragma unroll
    for (int i = 0; i < 7; ++i) hb[i] = hvp[i];

    // --- dot phase: fp16 dot2, f32 accumulate ---
    float a0 = 0.f, a1 = 0.f, a2 = 0.f, a3 = 0.f, a4 = 0.f, a5 = 0.f;
    #pragma unroll
    for (int p = 0; p < 25; ++p) {
      half2v h2 = ash2(hb[p >> 2][p & 3]);
      a0 = __builtin_amdgcn_fdot2(ash2(w[0][p]), h2, a0, false);
      a1 = __builtin_amdgcn_fdot2(ash2(w[1][p]), h2, a1, false);
      a2 = __builtin_amdgcn_fdot2(ash2(w[2][p]), h2, a2, false);
      a3 = __builtin_amdgcn_fdot2(ash2(w[3][p]), h2, a3, false);
      a4 = __builtin_amdgcn_fdot2(ash2(w[4][p]), h2, a4, false);
      a5 = __builtin_amdgcn_fdot2(ash2(w[5][p]), h2, a5, false);
    }
    const int pb = kq * 804;
    parts[pb + gs]        = a0;
    parts[pb + 128 + gs]  = a1;
    parts[pb + 256 + gs]  = a2;
    parts[pb + 384 + gs]  = a3;
    parts[pb + 512 + gs]  = a4;
    parts[pb + 640 + gs]  = a5;
    if (tail) {
      float a6 = 0.f;
      #pragma unroll
      for (int p = 0; p < 25; ++p)
        a6 = __builtin_amdgcn_fdot2(ash2(wt[p]), ash2(hb[p >> 2][p & 3]), a6, false);
      parts[pb + 672 + gs] = a6;   // gate 768+(gs-96)
    }
    __syncthreads();

    // --- reduce + nonlinearity (threads 0..199); no pads inside [0,len) ---
    if (u < 200) {
      float gi = parts[u]       + parts[804 + u]       + parts[1608 + u]       + parts[2412 + u]       + bI + bfr2f(qI);
      float gf = parts[200 + u] + parts[804 + 200 + u] + parts[1608 + 200 + u] + parts[2412 + 200 + u] + bF + bfr2f(qF);
      float gg = parts[400 + u] + parts[804 + 400 + u] + parts[1608 + 400 + u] + parts[2412 + 400 + u] + bG + bfr2f(qG);
      float go = parts[600 + u] + parts[804 + 600 + u] + parts[1608 + 600 + u] + parts[2412 + 600 + u] + bO + bfr2f(qO);
      float si = sigm(gi), sf = sigm(gf), so = sigm(go);
      float cn = sf * creg + si * tanh_f(gg);
      float hn = so * tanh_f(cn);
      creg = cn;
      hreg = hn;
      hsh[hwrite] = (_Float16)hn;
      out[((size_t)row * T + t) * ostride + dir * H + u] = __float2bfloat16(hn);
    }
    __syncthreads();
  }

  if (final_h != nullptr && u < 200) {
    // glob_h = [hb1 | hf1]: backward dir -> cols 0..199, forward -> 200..399
    int col = dir ? u : (H + u);
    final_h[(size_t)row * 400 + col] = hreg;
  }
}

// ---------------------------------------------------------------------------
// Span sums v2: chunked (t-chunk x d-octet) with bf16x8 row loads.
// Threads: tc = tid>>6 (t-chunk of 64), dv = tid&63 (d-octet, active < 50).
// Flag loads are wave-uniform (scalar); rows loaded only on span hits.
__global__ __launch_bounds__(256) void span_sum(
    const __hip_bfloat16* __restrict__ rnn,   // [B][T][400]
    const int* __restrict__ masks,
    const int* __restrict__ subj_pos,
    const int* __restrict__ obj_pos,
    float* __restrict__ obj_h,   // [B][400]
    float* __restrict__ subj_h)  // [B][400]
{
  int b = blockIdx.x;
  int tc = threadIdx.x >> 6;
  int dv = threadIdx.x & 63;
  __shared__ float aS[4][400];
  __shared__ float aO[4][400];

  float ss[8] = {}, so[8] = {};
  if (dv < 50) {
    for (int t = tc * 64; t < tc * 64 + 64; ++t) {
      int m = masks[b * T + t];
      int fs = (subj_pos[b * T + t] + m) == 0;
      int fo = (obj_pos[b * T + t] + m) == 0;
      if (fs | fo) {
        uix4 v = *(const uix4*)(rnn + ((size_t)b * T + t) * 400 + dv * 8);
        #pragma unroll
        for (int j = 0; j < 4; ++j) {
          float lo = bfr2f((unsigned short)(v[j] & 0xFFFF));
          float hi = bfr2f((unsigned short)(v[j] >> 16));
          if (fs) { ss[2 * j] += lo; ss[2 * j + 1] += hi; }
          if (fo) { so[2 * j] += lo; so[2 * j + 1] += hi; }
        }
      }
    }
    #pragma unroll
    for (int k = 0; k < 8; ++k) {
      aS[tc][dv * 8 + k] = ss[k];
      aO[tc][dv * 8 + k] = so[k];
    }
  }
  __syncthreads();
  for (int d = threadIdx.x; d < 400; d += 256) {
    subj_h[(size_t)b * 400 + d] = aS[0][d] + aS[1][d] + aS[2][d] + aS[3][d];
    obj_h[(size_t)b * 400 + d]  = aO[0][d] + aO[1][d] + aO[2][d] + aO[3][d];
  }
}

// ---------------------------------------------------------------------------
// Single-query attention pooling v2 (verified; round-11 fusion regressed).
// grid = 3*128 (qi = blk>>7, b = blk&127).
__global__ __launch_bounds__(256) void attn_pool_k(
    const float* __restrict__ qbuf,           // [3][B][400]
    const __hip_bfloat16* __restrict__ rnn,   // [B][T][400]
    const int* __restrict__ masks,
    float* __restrict__ outp)                 // [3][B][400]
{
  int b = blockIdx.x & 127;
  int qi = blockIdx.x >> 7;
  __shared__ float qs[400];
  __shared__ float ps[256];
  __shared__ float red[256];
  __shared__ float acc4[4][400];
  const float* q = qbuf + ((size_t)qi * B + b) * 400;
  for (int d = threadIdx.x; d < 400; d += 256) qs[d] = q[d];
  __syncthreads();

  int t = threadIdx.x;
  const uix4* kvv = (const uix4*)(rnn + ((size_t)b * T + t) * 400);
  float s = 0.f;
  #pragma unroll 5
  for (int i = 0; i < 50; ++i) {
    uix4 v = kvv[i];
    #pragma unroll
    for (int j = 0; j < 4; ++j) {
      s += bfr2f((unsigned short)(v[j] & 0xFFFF)) * qs[8 * i + 2 * j];
      s += bfr2f((unsigned short)(v[j] >> 16))    * qs[8 * i + 2 * j + 1];
    }
  }
  s *= 0.05f;  // 1/sqrt(400)
  if (masks[b * T + t] != 0) s = -1e9f;

  red[t] = s;
  __syncthreads();
  for (int off = 128; off > 0; off >>= 1) {
    if (t < off) red[t] = fmaxf(red[t], red[t + off]);
    __syncthreads();
  }
  float mx = red[0];
  __syncthreads();
  float e = expf(s - mx);
  red[t] = e;
  __syncthreads();
  for (int off = 128; off > 0; off >>= 1) {
    if (t < off) red[t] += red[t + off];
    __syncthreads();
  }
  float inv = 1.0f / red[0];
  ps[t] = e * inv;
  __syncthreads();

  // --- phase 2: out[d] = sum_t ps[t] * rnn[t][d], chunked ---
  int tc = threadIdx.x >> 6;
  int dv = threadIdx.x & 63;
  float a[8] = {};
  if (dv < 50) {
    for (int t2 = tc * 64; t2 < tc * 64 + 64; ++t2) {
      float wgt = ps[t2];              // wave-uniform (LDS broadcast)
      if (wgt != 0.f) {
        uix4 v = *(const uix4*)(rnn + ((size_t)b * T + t2) * 400 + dv * 8);
        #pragma unroll
        for (int j = 0; j < 4; ++j) {
          a[2 * j]     += wgt * bfr2f((unsigned short)(v[j] & 0xFFFF));
          a[2 * j + 1] += wgt * bfr2f((unsigned short)(v[j] >> 16));
        }
      }
    }
    #pragma unroll
    for (int k = 0; k < 8; ++k) acc4[tc][dv * 8 + k] = a[k];
  }
  __syncthreads();
  for (int d = threadIdx.x; d < 400; d += 256)
    outp[((size_t)qi * B + b) * 400 + d] =
        acc4[0][d] + acc4[1][d] + acc4[2][d] + acc4[3][d];
}

// ---------------------------------------------------------------------------
// Head — reads all weights raw (flag-dispatched), writes bf16 or f32 per flag
__global__ __launch_bounds__(256) void final_head(
    const float* __restrict__ attn,   // [3][B][400]: 0=obj,1=subj,2=glob
    const void* __restrict__ wo_w, const void* __restrict__ wo_b,
    const void* __restrict__ ws_w, const void* __restrict__ ws_b,
    const void* __restrict__ wg_w, const void* __restrict__ wg_b,
    const void* __restrict__ cls_w, const void* __restrict__ cls_b,
    void* __restrict__ outp,          // [B][2]
    const int* __restrict__ flag)
{
  int b = blockIdx.x;
  int f = *flag;
  __shared__ float hs[H];
  int j = threadIdx.x;
  if (j < H) {
    float acc = ldraw(wo_b, j, f) + ldraw(ws_b, j, f) + ldraw(wg_b, j, f);
    const float* oa = attn + ((size_t)0 * B + b) * 400;
    const float* sa = attn + ((size_t)1 * B + b) * 400;
    const float* ga = attn + ((size_t)2 * B + b) * 400;
    for (int d = 0; d < 400; ++d) {
      acc += oa[d] * ldraw(wo_w, (size_t)j * 400 + d, f);
      acc += sa[d] * ldraw(ws_w, (size_t)j * 400 + d, f);
      acc += ga[d] * ldraw(wg_w, (size_t)j * 400 + d, f);
    }
    hs[j] = fmaxf(acc, 0.0f);
  }
  __syncthreads();
  if (j < 2) {
    float a = ldraw(cls_b, j, f);
    for (int k = 0; k < H; ++k)
      a += hs[k] * ldraw(cls_w, (size_t)j * H + k, f);
    if (f) ((float*)outp)[b * 2 + j] = a;
    else   ((__hip_bfloat16*)outp)[b * 2 + j] = __float2bfloat16(a);
  }
}

// ---------------------------------------------------------------------------
// Workspace layout (bytes)
constexpr size_t O_X0   = 0;            // 32768*384*2  = 25165824
constexpr size_t O_X1   = 25165824;     // 32768*416*2  = 27262976
constexpr size_t O_GPRE = 52428800;     // 32768*1600*2 = 104857600
constexpr size_t O_RNN  = 157286400;    // 32768*400*2  = 26214400
constexpr size_t O_WIH0 = 183500800;    // 1600*384*2   = 1228800
constexpr size_t O_WIH1 = 184729600;    // 1600*416*2   = 1331200
constexpr size_t O_WPK  = 186060800;    // 4*800*100*4  = 1280000
constexpr size_t O_Q    = 187340800;    // 3*128*400*4  = 614400
constexpr size_t O_ATT  = 187955200;    // 614400
constexpr size_t O_FLAG = 188569600;    // 256

extern "C" void kernel_launch(void* const* d_in, const int* in_sizes, int n_in,
                              void* d_out, int out_size, void* d_ws, size_t ws_size,
                              hipStream_t stream) {
  (void)in_sizes; (void)n_in; (void)out_size; (void)ws_size;

  const int* words = (const int*)d_in[0];
  const int* masks = (const int*)d_in[1];
  const int* pos   = (const int*)d_in[2];
  const int* ner   = (const int*)d_in[3];
  const int* subj  = (const int*)d_in[4];
  const int* obj   = (const int*)d_in[5];
  const void* emb_w = d_in[6];
  const void* pos_w = d_in[7];
  const void* ner_w = d_in[8];
  const void* wih[4]  = {d_in[9],  d_in[12], d_in[15], d_in[18]};
  const void* whh[4]  = {d_in[10], d_in[13], d_in[16], d_in[19]};
  const void* bias[4] = {d_in[11], d_in[14], d_in[17], d_in[20]};
  const void* wo_w = d_in[21]; const void* wo_b = d_in[22];
  const void* ws_w = d_in[23]; const void* ws_b = d_in[24];
  const void* wg_w = d_in[25]; const void* wg_b = d_in[26];
  const void* cls_w = d_in[27]; const void* cls_b = d_in[28];

  char* ws = (char*)d_ws;
  __hip_bfloat16* X0   = (__hip_bfloat16*)(ws + O_X0);
  __hip_bfloat16* X1   = (__hip_bfloat16*)(ws + O_X1);
  __hip_bfloat16* Gpre = (__hip_bfloat16*)(ws + O_GPRE);   // [BT][1600]
  __hip_bfloat16* RNN  = (__hip_bfloat16*)(ws + O_RNN);
  __hip_bfloat16* wih0p = (__hip_bfloat16*)(ws + O_WIH0);  // [1600][384]
  __hip_bfloat16* wih1p = (__hip_bfloat16*)(ws + O_WIH1);  // [1600][416]
  unsigned* Wpack = (unsigned*)(ws + O_WPK);               // [4][800][100]
  float* qbuf = (float*)(ws + O_Q);    // [3][B][400]: obj, subj, glob
  float* attb = (float*)(ws + O_ATT);  // [3][B][400]
  int* flag = (int*)(ws + O_FLAG);

  // --- dtype detect + fully-merged prep (weights + embed + zero-fill) ---
  detect_dtype<<<1, 256, 0, stream>>>((const unsigned short*)emb_w, flag);
  prep_all<<<10594, 256, 0, stream>>>(
      whh[0], whh[1], whh[2], whh[3], Wpack,
      wih[0], wih[1], wih0p, wih[2], wih[3], wih1p,
      words, pos, ner, emb_w, pos_w, ner_w, X0,
      (uix4*)X1, (size_t)BT * K1P * 2 / 16,
      (uix4*)RNN, (size_t)BT * 400 * 2 / 16,
      flag);

  const int ggrid = (BT / 128) * 13;   // 3328, XCD-aware decode in-kernel

  // --- layer 0 ---
  gemm_bt<<<ggrid, 256, 0, stream>>>(X0, wih0p, Gpre, 1600, K0P);
  lstm_row<<<256, 512, 0, stream>>>(Gpre, Wpack, bias[0], bias[1], masks,
                                    X1, K1P, nullptr, flag);

  // --- layer 1 ---
  gemm_bt<<<ggrid, 256, 0, stream>>>(X1, wih1p, Gpre, 1600, K1P);
  float* qglob = qbuf + (size_t)2 * B * 400;
  lstm_row<<<256, 512, 0, stream>>>(Gpre, Wpack + (size_t)2 * G4 * 100,
                                    bias[2], bias[3], masks,
                                    RNN, 400, qglob, flag);

  // --- span sums (obj -> slot0, subj -> slot1) ---
  span_sum<<<B, 256, 0, stream>>>(RNN, masks, subj, obj,
                                  qbuf, qbuf + (size_t)B * 400);

  // --- attention pooling (3 queries, v2) ---
  attn_pool_k<<<3 * B, 256, 0, stream>>>(qbuf, RNN, masks, attb);

  // --- head (raw weights) ---
  final_head<<<B, 256, 0, stream>>>(attb, wo_w, wo_b, ws_w, ws_b, wg_w, wg_b,
                                    cls_w, cls_b, d_out, flag);
}